// Round 3
// baseline (1387.429 us; speedup 1.0000x reference)
//
#include <hip/hip_runtime.h>
#include <cstdint>
#include <cstddef>

#define TB 2
#define TS 2048
#define TD 4096
#define TH 16
#define THD 256
#define TROT 64
#define TM (TB*TS)

typedef __attribute__((ext_vector_type(8))) short bf16x8;
typedef __attribute__((ext_vector_type(4))) float f32x4;

__device__ __forceinline__ unsigned short f2bf(float f) {
  union { float f; unsigned u; } v; v.f = f;
  return (unsigned short)((v.u + 0x7fffu + ((v.u >> 16) & 1u)) >> 16);
}

__device__ __forceinline__ void gld16(const void* g, void* l) {
  __builtin_amdgcn_global_load_lds(
      (const __attribute__((address_space(1))) unsigned int*)g,
      (__attribute__((address_space(3))) unsigned int*)l, 16, 0, 0);
}

// ---------------- fp32 -> bf16 convert (vectorized) ----------------
__global__ __launch_bounds__(256) void k_cvt(const float* __restrict__ x,
                                             unsigned short* __restrict__ y, int n4) {
  int i = blockIdx.x * 256 + threadIdx.x;
  if (i >= n4) return;
  float4 v = reinterpret_cast<const float4*>(x)[i];
  ushort4 o;
  o.x = f2bf(v.x); o.y = f2bf(v.y); o.z = f2bf(v.z); o.w = f2bf(v.w);
  reinterpret_cast<ushort4*>(y)[i] = o;
}

// ---------------- GEMM: C = A (MxK,bf16) @ W^T (W: NxK,bf16) ----------------
// m97 structure: 128x128 tile, BK=32, global_load_lds width=16, linear LDS.
// 1D grid (1024 blocks) with XCD-aware swizzle (T1).
// MODE 0: fp32 out, row-major [M,N]
// MODE 1: RoPE + transpose epilogue -> bf16 out [B,H,S,HD]
// MODE 2: V^T epilogue via LDS transpose -> bf16 out [B,H,HD,S], coalesced
template<int MODE>
__global__ __launch_bounds__(256) void k_gemm(
    const unsigned short* __restrict__ A, const unsigned short* __restrict__ W,
    void* __restrict__ out, const float* __restrict__ sinp, const float* __restrict__ cosp)
{
  __shared__ unsigned short sh[2*128*32];   // As | Bs (16 KB), reused by epilogue
  unsigned short* As = sh;
  unsigned short* Bs = sh + 128*32;
  const int K = TD;
  const int t = threadIdx.x;

  // XCD swizzle: grid = 1024 = 8 XCD x 128; each XCD gets a contiguous chunk.
  const int id = blockIdx.x;
  const int swz = (id & 7) * 128 + (id >> 3);
  const int m0 = (swz >> 5) * 128, n0 = (swz & 31) * 128;

  const int w = t >> 6, l = t & 63, lr = l & 15, lh = l >> 4;
  const int wr = (w >> 1) * 64, wc = (w & 1) * 64;

  // wave w stages rows [32w, 32w+32) of A and B (wave-uniform LDS base + lane*16B)
  const int i0 = w * 2, i1 = w * 2 + 1;
  const size_t ao0 = (size_t)(m0 + i0*16 + (l >> 2)) * K + (l & 3) * 8;
  const size_t ao1 = (size_t)(m0 + i1*16 + (l >> 2)) * K + (l & 3) * 8;
  const size_t bo0 = (size_t)(n0 + i0*16 + (l >> 2)) * K + (l & 3) * 8;
  const size_t bo1 = (size_t)(n0 + i1*16 + (l >> 2)) * K + (l & 3) * 8;
  unsigned short* la0 = &As[i0 * 512];
  unsigned short* la1 = &As[i1 * 512];
  unsigned short* lb0 = &Bs[i0 * 512];
  unsigned short* lb1 = &Bs[i1 * 512];

  f32x4 acc[4][4];
#pragma unroll
  for (int i = 0; i < 4; ++i)
#pragma unroll
    for (int j = 0; j < 4; ++j) acc[i][j] = 0.f;

  for (int kt = 0; kt < K / 32; ++kt) {
    const int ko = kt * 32;
    __syncthreads();
    gld16(A + ao0 + ko, la0);
    gld16(A + ao1 + ko, la1);
    gld16(W + bo0 + ko, lb0);
    gld16(W + bo1 + ko, lb1);
    __syncthreads();
    bf16x8 af[4], bfr[4];
#pragma unroll
    for (int i = 0; i < 4; ++i) af[i]  = *(const bf16x8*)&As[(wr + i*16 + lr)*32 + lh*8];
#pragma unroll
    for (int i = 0; i < 4; ++i) bfr[i] = *(const bf16x8*)&Bs[(wc + i*16 + lr)*32 + lh*8];
#pragma unroll
    for (int i = 0; i < 4; ++i)
#pragma unroll
      for (int j = 0; j < 4; ++j)
        acc[i][j] = __builtin_amdgcn_mfma_f32_16x16x32_bf16(af[i], bfr[j], acc[i][j], 0, 0, 0);
  }

  if constexpr (MODE == 2) {
    // Block-wide LDS transpose -> coalesced V^T rows [B,H,HD,S].
    // 4 chunks of 32 output rows (d); buffer [32][136] shorts (8.7 KB) in sh.
    const int b = m0 >> 11, sbase = m0 & (TS - 1);
#pragma unroll
    for (int c = 0; c < 4; ++c) {
      __syncthreads();
      if ((w & 1) == (c >> 1)) {
#pragma unroll
        for (int j2 = 0; j2 < 2; ++j2) {
          int j = (c & 1) * 2 + j2;
#pragma unroll
          for (int i = 0; i < 4; ++i)
#pragma unroll
            for (int r = 0; r < 4; ++r)
              sh[(j2*16 + lr) * 136 + (wr + i*16 + lh*4 + r)] = f2bf(acc[i][j][r]);
        }
      }
      __syncthreads();
#pragma unroll
      for (int it = 0; it < 2; ++it) {
        int idx = t + it * 256;              // 512 chunks: 32 rows x 16 x 16B
        int dl = idx >> 4, sj = (idx & 15) * 8;
        uint4 v = *(const uint4*)&sh[dl * 136 + sj];
        int d = n0 + c * 32 + dl;
        int h = d >> 8, dd = d & 255;
        *(uint4*)((unsigned short*)out +
                  ((size_t)((b*TH + h)*THD + dd)) * TS + sbase + sj) = v;
      }
    }
  } else {
#pragma unroll
    for (int i = 0; i < 4; ++i)
#pragma unroll
      for (int j = 0; j < 4; ++j)
#pragma unroll
        for (int r = 0; r < 4; ++r) {
          int row = m0 + wr + i*16 + lh*4 + r;   // C layout: row=(l>>4)*4+r
          int col = n0 + wc + j*16 + lr;         //            col=l&15
          float x = acc[i][j][r];
          if constexpr (MODE == 0) {
            ((float*)out)[(size_t)row * TD + col] = x;
          } else {
            float part = __shfl_xor(x, 1, 64);   // partner d^1 lives in lane l^1
            int s = row & (TS - 1), b = row >> 11;
            int h = col >> 8, d = col & 255;
            float val = x;
            if (d < TROT) {
              float cc = cosp[s * TROT + d], ss = sinp[s * TROT + d];
              val = x * cc + ((d & 1) ? part : -part) * ss;  // GPT-J rotate_every_two
            }
            ((unsigned short*)out)[((size_t)(b * TH + h) * TS + s) * THD + d] = f2bf(val);
          }
        }
  }
}

// ---------------- causal flash attention ----------------
// Qt,Kt: [B,H,S,HD] bf16.  Vt: [B,H,HD,S] bf16 (V^T).  O: [B,S,H,HD] bf16.
// block = 4 waves; wave w owns q rows [q0+16w, q0+16w+16); KV tile = 32.
// launch_bounds(256,1): allow ~200 VGPRs (no spill), 2 blocks/CU.
__global__ __launch_bounds__(256, 1) void k_fattn(
    const unsigned short* __restrict__ Qt, const unsigned short* __restrict__ Kt,
    const unsigned short* __restrict__ Vt, unsigned short* __restrict__ O)
{
  __shared__ unsigned short Ks[32*264];    // 32 x (256+8 pad)
  __shared__ unsigned short Vs[256*40];    // V^T tile: [d][s_local], 32+8 pad
  __shared__ unsigned short Ps[4*16*40];   // per-wave P relayout (wave-private)
  const int t = threadIdx.x, w = t >> 6, l = t & 63, lr = l & 15, lh = l >> 4;
  const int bh = blockIdx.x;
  const int qb = (gridDim.y - 1) - blockIdx.y;   // LPT: heaviest first
  const int q0 = qb * 64;
  const int jmax = 2 * qb + 1;

  const unsigned short* kbase = Kt + (size_t)bh * TS * THD;
  const unsigned short* vbase = Vt + (size_t)bh * THD * TS;

  bf16x8 qf[8];
  const unsigned short* qb_ = Qt + ((size_t)bh * TS + q0 + w*16 + lr) * THD;
#pragma unroll
  for (int kk = 0; kk < 8; ++kk) qf[kk] = *(const bf16x8*)(qb_ + kk*32 + lh*8);

  f32x4 oacc[16];
#pragma unroll
  for (int i = 0; i < 16; ++i) oacc[i] = 0.f;
  float mrow[4] = {-__builtin_inff(), -__builtin_inff(), -__builtin_inff(), -__builtin_inff()};
  float lrow[4] = {0.f, 0.f, 0.f, 0.f};

  // staging maps (chunk c = t + it*256):
  //  K: row = c>>5 (32), col = (c&31)*8;  V: d = c>>2 (256), col = (c&3)*8
  uint4 ka[4], va[4];
#pragma unroll
  for (int it = 0; it < 4; ++it) {
    int c = t + it * 256;
    ka[it] = *(const uint4*)(kbase + (size_t)(c >> 5) * THD + (c & 31) * 8);
    va[it] = *(const uint4*)(vbase + (size_t)(c >> 2) * TS + (c & 3) * 8);
  }

  for (int j = 0; j <= jmax; ++j) {
    __syncthreads();
#pragma unroll
    for (int it = 0; it < 4; ++it) {
      int c = t + it * 256;
      *(uint4*)&Ks[(c >> 5) * 264 + (c & 31) * 8] = ka[it];
      *(uint4*)&Vs[(c >> 2) * 40  + (c & 3)  * 8] = va[it];
    }
    __syncthreads();

    if (j < jmax) {   // T14: issue next tile's loads, hide latency under compute
      int jn = (j + 1) * 32;
#pragma unroll
      for (int it = 0; it < 4; ++it) {
        int c = t + it * 256;
        ka[it] = *(const uint4*)(kbase + (size_t)(jn + (c >> 5)) * THD + (c & 31) * 8);
        va[it] = *(const uint4*)(vbase + (size_t)(c >> 2) * TS + jn + (c & 3) * 8);
      }
    }

    // S = Q K^T
    f32x4 sacc[2];
    sacc[0] = 0.f; sacc[1] = 0.f;
    __builtin_amdgcn_s_setprio(1);
#pragma unroll
    for (int nt = 0; nt < 2; ++nt)
#pragma unroll
      for (int kk = 0; kk < 8; ++kk) {
        bf16x8 kf = *(const bf16x8*)&Ks[(nt*16 + lr)*264 + kk*32 + lh*8];
        sacc[nt] = __builtin_amdgcn_mfma_f32_16x16x32_bf16(qf[kk], kf, sacc[nt], 0, 0, 0);
      }
    __builtin_amdgcn_s_setprio(0);

    // online softmax (C layout: row = lh*4+r, col = nt*16+lr)
    float p[2][4], tmax[4], tsum[4], alpha[4];
    const int qrb = q0 + w*16 + lh*4;
#pragma unroll
    for (int r = 0; r < 4; ++r) tmax[r] = -__builtin_inff();
#pragma unroll
    for (int nt = 0; nt < 2; ++nt) {
      int kpos = j*32 + nt*16 + lr;
#pragma unroll
      for (int r = 0; r < 4; ++r) {
        float sv = sacc[nt][r] * 0.0625f;           // 1/sqrt(256)
        if (kpos > qrb + r) sv = -__builtin_inff(); // causal mask
        p[nt][r] = sv;
        tmax[r] = fmaxf(tmax[r], sv);
      }
    }
#pragma unroll
    for (int off = 1; off < 16; off <<= 1)
#pragma unroll
      for (int r = 0; r < 4; ++r) tmax[r] = fmaxf(tmax[r], __shfl_xor(tmax[r], off, 64));
#pragma unroll
    for (int r = 0; r < 4; ++r) {
      float mn = fmaxf(mrow[r], tmax[r]);
      alpha[r] = __expf(mrow[r] - mn);
      mrow[r] = mn;
      tsum[r] = 0.f;
    }
#pragma unroll
    for (int nt = 0; nt < 2; ++nt)
#pragma unroll
      for (int r = 0; r < 4; ++r) {
        float pe = __expf(p[nt][r] - mrow[r]);
        p[nt][r] = pe;
        tsum[r] += pe;
      }
#pragma unroll
    for (int off = 1; off < 16; off <<= 1)
#pragma unroll
      for (int r = 0; r < 4; ++r) tsum[r] += __shfl_xor(tsum[r], off, 64);
#pragma unroll
    for (int r = 0; r < 4; ++r) lrow[r] = lrow[r] * alpha[r] + tsum[r];
#pragma unroll
    for (int i = 0; i < 16; ++i)
#pragma unroll
      for (int r = 0; r < 4; ++r) oacc[i][r] *= alpha[r];

    // P: C layout -> A-fragment layout via wave-private LDS (no barrier needed)
#pragma unroll
    for (int nt = 0; nt < 2; ++nt)
#pragma unroll
      for (int r = 0; r < 4; ++r)
        Ps[w*640 + (lh*4 + r)*40 + nt*16 + lr] = f2bf(p[nt][r]);
    bf16x8 pf = *(const bf16x8*)&Ps[w*640 + lr*40 + lh*8];

    // O += P V
    __builtin_amdgcn_s_setprio(1);
#pragma unroll
    for (int dt = 0; dt < 16; ++dt) {
      bf16x8 vf = *(const bf16x8*)&Vs[(dt*16 + lr)*40 + lh*8];
      oacc[dt] = __builtin_amdgcn_mfma_f32_16x16x32_bf16(pf, vf, oacc[dt], 0, 0, 0);
    }
    __builtin_amdgcn_s_setprio(0);
  }

  // epilogue: O[b][s][h][d] bf16
  const int b = bh >> 4, h = bh & 15;
  float inv[4];
#pragma unroll
  for (int r = 0; r < 4; ++r) inv[r] = 1.f / lrow[r];
#pragma unroll
  for (int dt = 0; dt < 16; ++dt)
#pragma unroll
    for (int r = 0; r < 4; ++r) {
      int s = q0 + w*16 + lh*4 + r;
      O[((size_t)(b*TS + s) * TH + h) * THD + dt*16 + lr] = f2bf(oacc[dt][r] * inv[r]);
    }
}

// ---------------- launch ----------------
extern "C" void kernel_launch(void* const* d_in, const int* in_sizes, int n_in,
                              void* d_out, int out_size, void* d_ws, size_t ws_size,
                              hipStream_t stream) {
  const float* hs   = (const float*)d_in[0];
  const float* sinp = (const float*)d_in[1];
  const float* cosp = (const float*)d_in[2];
  const float* Wq   = (const float*)d_in[3];
  const float* Wk   = (const float*)d_in[4];
  const float* Wv   = (const float*)d_in[5];
  const float* Wo   = (const float*)d_in[6];

  const size_t NE = (size_t)TM * TD;
  const size_t BYTES = NE * 2;
  char* ws = (char*)d_ws;
  unsigned short* hsb = (unsigned short*)(ws + 0*BYTES);
  unsigned short* Wqb = (unsigned short*)(ws + 1*BYTES);
  unsigned short* Wkb = (unsigned short*)(ws + 2*BYTES);
  unsigned short* Wvb = (unsigned short*)(ws + 3*BYTES);
  unsigned short* Wob = (unsigned short*)(ws + 4*BYTES);
  unsigned short* Qt  = (unsigned short*)(ws + 5*BYTES);  // [B,H,S,HD]
  unsigned short* Ktb = (unsigned short*)(ws + 6*BYTES);  // [B,H,S,HD]
  unsigned short* Vtb = (unsigned short*)(ws + 7*BYTES);  // [B,H,HD,S]  (V^T)
  unsigned short* Ob  = (unsigned short*)(ws + 8*BYTES);  // [B,S,H,HD] == [M,D]

  int n4 = (int)(NE / 4);
  int cvb = (n4 + 255) / 256;
  k_cvt<<<cvb, 256, 0, stream>>>(hs, hsb, n4);
  k_cvt<<<cvb, 256, 0, stream>>>(Wq, Wqb, n4);
  k_cvt<<<cvb, 256, 0, stream>>>(Wk, Wkb, n4);
  k_cvt<<<cvb, 256, 0, stream>>>(Wv, Wvb, n4);
  k_cvt<<<cvb, 256, 0, stream>>>(Wo, Wob, n4);

  k_gemm<1><<<1024, 256, 0, stream>>>(hsb, Wqb, (void*)Qt,  sinp, cosp);
  k_gemm<1><<<1024, 256, 0, stream>>>(hsb, Wkb, (void*)Ktb, sinp, cosp);
  k_gemm<2><<<1024, 256, 0, stream>>>(hsb, Wvb, (void*)Vtb, nullptr, nullptr);

  k_fattn<<<dim3(TB*TH, TS/64), 256, 0, stream>>>(Qt, Ktb, Vtb, Ob);

  k_gemm<0><<<1024, 256, 0, stream>>>(Ob, Wob, d_out, nullptr, nullptr);
}

// Round 4
// 867.361 us; speedup vs baseline: 1.5996x; 1.5996x over previous
//
#include <hip/hip_runtime.h>
#include <cstdint>
#include <cstddef>

#define TB 2
#define TS 2048
#define TD 4096
#define TH 16
#define THD 256
#define TROT 64
#define TM (TB*TS)

typedef __attribute__((ext_vector_type(8))) short bf16x8;
typedef __attribute__((ext_vector_type(4))) float f32x4;

#define LGKM0  asm volatile("s_waitcnt lgkmcnt(0)" ::: "memory")
#define VMCNT4 asm volatile("s_waitcnt vmcnt(4)" ::: "memory")
#define VMCNT0 asm volatile("s_waitcnt vmcnt(0)" ::: "memory")
#define SBAR   __builtin_amdgcn_s_barrier()
#define SCHED0 __builtin_amdgcn_sched_barrier(0)

__device__ __forceinline__ unsigned short f2bf(float f) {
  union { float f; unsigned u; } v; v.f = f;
  return (unsigned short)((v.u + 0x7fffu + ((v.u >> 16) & 1u)) >> 16);
}

__device__ __forceinline__ void gld16(const void* g, void* l) {
  __builtin_amdgcn_global_load_lds(
      (const __attribute__((address_space(1))) unsigned int*)g,
      (__attribute__((address_space(3))) unsigned int*)l, 16, 0, 0);
}

// ---------------- fp32 -> bf16 convert ----------------
__global__ __launch_bounds__(256) void k_cvt(const float* __restrict__ x,
                                             unsigned short* __restrict__ y, int n4) {
  int i = blockIdx.x * 256 + threadIdx.x;
  if (i >= n4) return;
  float4 v = reinterpret_cast<const float4*>(x)[i];
  ushort4 o;
  o.x = f2bf(v.x); o.y = f2bf(v.y); o.z = f2bf(v.z); o.w = f2bf(v.w);
  reinterpret_cast<ushort4*>(y)[i] = o;
}

// ---------------- GEMM 256x256, BK=32, 8 waves, 4-phase, dbuf ----------------
// C = A(MxK) @ W^T (W: NxK), bf16 in, layouts per MODE.
// LDS (64KB): [buf0 A 16K][buf0 B 16K][buf1 A][buf1 B]; subtiled [16][32] with
// row-bit3 XOR swizzle applied via pre-swizzled global source (gld16 linear dest).
// MODE 0: fp32 out [M,N]; MODE 1: RoPE+transpose -> bf16 [B,H,S,HD];
// MODE 2: V^T -> bf16 [B,H,HD,S] via LDS-bounce transpose.
template<int MODE>
__global__ __launch_bounds__(512, 2) void k_gemm(
    const unsigned short* __restrict__ A, const unsigned short* __restrict__ W,
    void* __restrict__ out, const float* __restrict__ sinp, const float* __restrict__ cosp)
{
  __shared__ unsigned short lds[32768];   // 64KB
  const int K = TD;
  const int t = threadIdx.x;
  const int w = t >> 6, l = t & 63, lr = l & 15, lh = l >> 4;
  const int wr = w >> 2, wc = w & 3;      // 2 x 4 waves; wave block 128x64

  // XCD swizzle (256 blocks = 8 XCD x 32, bijective)
  const int id = blockIdx.x;
  const int swz = (id & 7) * 32 + (id >> 3);
  const int m0 = (swz >> 4) * 256, n0 = (swz & 15) * 256;

  // per-lane LDS read offset within a [16][32] subtile (shorts), bit3-row XOR
  const int llo = lr * 32 + ((lh * 8) ^ (((lr >> 3) & 1) << 4));

  // staging source precompute: chunk c covers LDS bytes [c*16, c*16+16)
  // row = (c>>6)*16 + ((c>>2)&15); src col-chunk = (c&3) ^ (((c>>5)&1)<<1)
  size_t offA[2], offB[2];
#pragma unroll
  for (int it = 0; it < 2; ++it) {
    int c = it * 512 + t;
    int row = (c >> 6) * 16 + ((c >> 2) & 15);
    int cch = (c & 3) ^ (((c >> 5) & 1) << 1);
    offA[it] = (size_t)(m0 + row) * K + cch * 8;
    offB[it] = (size_t)(n0 + row) * K + cch * 8;
  }

  f32x4 acc[8][4];
#pragma unroll
  for (int i = 0; i < 8; ++i)
#pragma unroll
    for (int j = 0; j < 4; ++j) acc[i][j] = 0.f;

  // prologue: stage tiles 0 (buf0) and 1 (buf1); B first, then A (per-buffer)
  gld16(W + offB[0], &lds[8192 + t*8]);
  gld16(W + offB[1], &lds[8192 + (512+t)*8]);
  gld16(A + offA[0], &lds[t*8]);
  gld16(A + offA[1], &lds[(512+t)*8]);
  gld16(W + offB[0] + 32, &lds[16384 + 8192 + t*8]);
  gld16(W + offB[1] + 32, &lds[16384 + 8192 + (512+t)*8]);
  gld16(A + offA[0] + 32, &lds[16384 + t*8]);
  gld16(A + offA[1] + 32, &lds[16384 + (512+t)*8]);
  VMCNT4;   // tile0 resident (tile1's 4 loads may remain)
  SBAR;
  SCHED0;

  const int abase = wr * 8 * 512;         // A subtile base (shorts) for this wave
  const int bbase = 8192 + wc * 4 * 512;  // B subtile base

  for (int i2 = 0; i2 < 64; ++i2) {
    const bool pf = (i2 < 63);
    const int ke2 = (i2 + 1) * 64;        // k-elem offset of tile t0+2
    bf16x8 af[4], bfr[4];

    // ---- phase 1: buf0, m0-3 ----
#pragma unroll
    for (int n = 0; n < 4; ++n)  bfr[n] = *(const bf16x8*)&lds[bbase + n*512 + llo];
#pragma unroll
    for (int mi = 0; mi < 4; ++mi) af[mi] = *(const bf16x8*)&lds[abase + mi*512 + llo];
    LGKM0; SBAR; SCHED0;
    if (pf) {   // restage buf0.B (last read was just drained)
      gld16(W + offB[0] + ke2, &lds[8192 + t*8]);
      gld16(W + offB[1] + ke2, &lds[8192 + (512+t)*8]);
    }
    __builtin_amdgcn_s_setprio(1);
#pragma unroll
    for (int mi = 0; mi < 4; ++mi)
#pragma unroll
      for (int n = 0; n < 4; ++n)
        acc[mi][n] = __builtin_amdgcn_mfma_f32_16x16x32_bf16(af[mi], bfr[n], acc[mi][n], 0,0,0);
    __builtin_amdgcn_s_setprio(0);
    SBAR;

    // ---- phase 2: buf0, m4-7 ----
#pragma unroll
    for (int mi = 0; mi < 4; ++mi) af[mi] = *(const bf16x8*)&lds[abase + (4+mi)*512 + llo];
    LGKM0; SBAR; SCHED0;
    if (pf) {
      gld16(A + offA[0] + ke2, &lds[t*8]);
      gld16(A + offA[1] + ke2, &lds[(512+t)*8]);
    }
    __builtin_amdgcn_s_setprio(1);
#pragma unroll
    for (int mi = 0; mi < 4; ++mi)
#pragma unroll
      for (int n = 0; n < 4; ++n)
        acc[4+mi][n] = __builtin_amdgcn_mfma_f32_16x16x32_bf16(af[mi], bfr[n], acc[4+mi][n], 0,0,0);
    __builtin_amdgcn_s_setprio(0);
    if (pf) { VMCNT4; } else { VMCNT0; }  // tile t1 resident
    SBAR; SCHED0;

    // ---- phase 3: buf1, m0-3 ----
#pragma unroll
    for (int n = 0; n < 4; ++n)  bfr[n] = *(const bf16x8*)&lds[16384 + bbase + n*512 + llo];
#pragma unroll
    for (int mi = 0; mi < 4; ++mi) af[mi] = *(const bf16x8*)&lds[16384 + abase + mi*512 + llo];
    LGKM0; SBAR; SCHED0;
    if (pf) {
      gld16(W + offB[0] + ke2 + 32, &lds[16384 + 8192 + t*8]);
      gld16(W + offB[1] + ke2 + 32, &lds[16384 + 8192 + (512+t)*8]);
    }
    __builtin_amdgcn_s_setprio(1);
#pragma unroll
    for (int mi = 0; mi < 4; ++mi)
#pragma unroll
      for (int n = 0; n < 4; ++n)
        acc[mi][n] = __builtin_amdgcn_mfma_f32_16x16x32_bf16(af[mi], bfr[n], acc[mi][n], 0,0,0);
    __builtin_amdgcn_s_setprio(0);
    SBAR;

    // ---- phase 4: buf1, m4-7 ----
#pragma unroll
    for (int mi = 0; mi < 4; ++mi) af[mi] = *(const bf16x8*)&lds[16384 + abase + (4+mi)*512 + llo];
    LGKM0; SBAR; SCHED0;
    if (pf) {
      gld16(A + offA[0] + ke2 + 32, &lds[16384 + t*8]);
      gld16(A + offA[1] + ke2 + 32, &lds[16384 + (512+t)*8]);
    }
    __builtin_amdgcn_s_setprio(1);
#pragma unroll
    for (int mi = 0; mi < 4; ++mi)
#pragma unroll
      for (int n = 0; n < 4; ++n)
        acc[4+mi][n] = __builtin_amdgcn_mfma_f32_16x16x32_bf16(af[mi], bfr[n], acc[4+mi][n], 0,0,0);
    __builtin_amdgcn_s_setprio(0);
    if (pf) { VMCNT4; } else { VMCNT0; }  // tile t0+2 resident
    SBAR; SCHED0;
  }

  // -------- epilogues --------
  if constexpr (MODE == 2) {
    // V^T [B,H,HD,S] via LDS transpose; CT = [64][280] shorts (35KB), 4 passes.
    const int b = m0 >> 11, sbase = m0 & (TS - 1);
#pragma unroll
    for (int p = 0; p < 4; ++p) {
      __syncthreads();
      if (wc == p) {
#pragma unroll
        for (int m = 0; m < 8; ++m)
#pragma unroll
          for (int n = 0; n < 4; ++n) {
            int lcol = n * 16 + lr;
            int srow = wr * 128 + m * 16 + lh * 4;
            ushort4 o;
            o.x = f2bf(acc[m][n][0]); o.y = f2bf(acc[m][n][1]);
            o.z = f2bf(acc[m][n][2]); o.w = f2bf(acc[m][n][3]);
            *(ushort4*)&lds[lcol * 280 + srow] = o;
          }
      }
      __syncthreads();
#pragma unroll
      for (int i = 0; i < 4; ++i) {
        int q = i * 512 + t;
        int dl = q >> 5, sc = q & 31;
        uint4 v = *(const uint4*)&lds[dl * 280 + sc * 8];
        int d = n0 + p * 64 + dl;
        *(uint4*)((unsigned short*)out +
                  ((size_t)((b * TH + (d >> 8)) * THD + (d & 255))) * TS + sbase + sc * 8) = v;
      }
    }
  } else {
#pragma unroll
    for (int m = 0; m < 8; ++m)
#pragma unroll
      for (int n = 0; n < 4; ++n)
#pragma unroll
        for (int r = 0; r < 4; ++r) {
          int row = m0 + wr * 128 + m * 16 + lh * 4 + r;
          int col = n0 + wc * 64 + n * 16 + lr;
          float x = acc[m][n][r];
          if constexpr (MODE == 0) {
            ((float*)out)[(size_t)row * TD + col] = x;
          } else {
            float part = __shfl_xor(x, 1, 64);
            int s = row & (TS - 1), b = row >> 11;
            int h = col >> 8, d = col & 255;
            float val = x;
            if (d < TROT) {
              float cc = cosp[s * TROT + d], ss = sinp[s * TROT + d];
              val = x * cc + ((d & 1) ? part : -part) * ss;
            }
            ((unsigned short*)out)[((size_t)(b * TH + h) * TS + s) * THD + d] = f2bf(val);
          }
        }
  }
}

// ---------------- causal flash attention ----------------
// Qt,Kt: [B,H,S,HD] bf16.  Vt: [B,H,HD,S] bf16.  O: [B,S,H,HD] bf16.
// 4 waves; wave w owns q rows [q0+16w,+16); KV tile 32. gld16 staging
// (zero staging VGPRs), staggered single-buffer K/V, counted vmcnt(4).
__global__ __launch_bounds__(256, 3) void k_fattn(
    const unsigned short* __restrict__ Qt, const unsigned short* __restrict__ Kt,
    const unsigned short* __restrict__ Vt, unsigned short* __restrict__ O)
{
  __shared__ unsigned short sh[18944];   // K 8192 | V 8192 | Ps 2560 (shorts)
  const int t = threadIdx.x, w = t >> 6, l = t & 63, lr = l & 15, lh = l >> 4;
  const int bh = blockIdx.x;
  const int qb = (gridDim.y - 1) - blockIdx.y;   // LPT: heaviest first
  const int q0 = qb * 64;
  const int jmax = 2 * qb + 1;

  const unsigned short* kbase = Kt + (size_t)bh * TS * THD;
  const unsigned short* vbase = Vt + (size_t)bh * THD * TS;

  const int llo = lr * 32 + ((lh * 8) ^ (((lr >> 3) & 1) << 4));  // K-read swizzle
  const int fv  = (lr & 3) ^ ((lr >> 2) & 1);                     // V-read swizzle

  // staging source offsets (chunk c = it*256 + t)
  size_t koff[4], voff[4];
#pragma unroll
  for (int it = 0; it < 4; ++it) {
    int c = it * 256 + t;
    int rl = (c >> 2) & 15;
    int krow = ((c >> 9) & 1) * 16 + rl;
    int kcch = (c & 3) ^ (((rl >> 3) & 1) << 1);
    koff[it] = (size_t)krow * THD + (((c >> 6) & 7) * 32 + kcch * 8);
    int vrow = c >> 2;
    int vcch = (c & 3) ^ (((vrow & 3)) ^ (((vrow >> 2) & 1) & 1));
    vcch = (c & 3) ^ ((vrow & 3) ^ ((vrow >> 2) & 1));
    voff[it] = (size_t)vrow * TS + vcch * 8;
  }

  bf16x8 qf[8];
  const unsigned short* qp = Qt + ((size_t)bh * TS + q0 + w * 16 + lr) * THD;
#pragma unroll
  for (int kk = 0; kk < 8; ++kk) qf[kk] = *(const bf16x8*)(qp + kk * 32 + lh * 8);

  f32x4 oacc[16];
#pragma unroll
  for (int i = 0; i < 16; ++i) oacc[i] = 0.f;
  float mrow[4] = {-__builtin_inff(), -__builtin_inff(), -__builtin_inff(), -__builtin_inff()};
  float lrow[4] = {0.f, 0.f, 0.f, 0.f};

  // prologue: stage K[0] then V[0]
#pragma unroll
  for (int it = 0; it < 4; ++it) gld16(kbase + koff[it], &sh[(it*256 + t) * 8]);
#pragma unroll
  for (int it = 0; it < 4; ++it) gld16(vbase + voff[it], &sh[8192 + (it*256 + t) * 8]);

  for (int j = 0; j <= jmax; ++j) {
    const bool nx = (j < jmax);
    VMCNT4;          // K[j] resident (V[j]'s 4 loads may remain)
    SBAR; SCHED0;

    // ---- QK^T ----
    f32x4 sacc[2];
    sacc[0] = 0.f; sacc[1] = 0.f;
    __builtin_amdgcn_s_setprio(1);
#pragma unroll
    for (int nt = 0; nt < 2; ++nt)
#pragma unroll
      for (int kk = 0; kk < 8; ++kk) {
        bf16x8 kf = *(const bf16x8*)&sh[(nt*8 + kk)*512 + llo];
        sacc[nt] = __builtin_amdgcn_mfma_f32_16x16x32_bf16(qf[kk], kf, sacc[nt], 0, 0, 0);
      }
    __builtin_amdgcn_s_setprio(0);
    LGKM0; SBAR; SCHED0;
    if (nx) {        // restage K for j+1 (async, covered by softmax+PV)
      const unsigned short* kj = kbase + (size_t)(j + 1) * 32 * THD;
#pragma unroll
      for (int it = 0; it < 4; ++it) gld16(kj + koff[it], &sh[(it*256 + t) * 8]);
    }

    // ---- online softmax ----
    float p[2][4], tmax[4], tsum[4], alpha[4];
    const int qrb = q0 + w * 16 + lh * 4;
#pragma unroll
    for (int r = 0; r < 4; ++r) tmax[r] = -__builtin_inff();
#pragma unroll
    for (int nt = 0; nt < 2; ++nt) {
      int kpos = j * 32 + nt * 16 + lr;
#pragma unroll
      for (int r = 0; r < 4; ++r) {
        float sv = sacc[nt][r] * 0.0625f;
        if (kpos > qrb + r) sv = -__builtin_inff();
        p[nt][r] = sv;
        tmax[r] = fmaxf(tmax[r], sv);
      }
    }
#pragma unroll
    for (int off = 1; off < 16; off <<= 1)
#pragma unroll
      for (int r = 0; r < 4; ++r) tmax[r] = fmaxf(tmax[r], __shfl_xor(tmax[r], off, 64));
#pragma unroll
    for (int r = 0; r < 4; ++r) {
      float mn = fmaxf(mrow[r], tmax[r]);
      alpha[r] = __expf(mrow[r] - mn);
      mrow[r] = mn;
      tsum[r] = 0.f;
    }
#pragma unroll
    for (int nt = 0; nt < 2; ++nt)
#pragma unroll
      for (int r = 0; r < 4; ++r) {
        float pe = __expf(p[nt][r] - mrow[r]);
        p[nt][r] = pe;
        tsum[r] += pe;
      }
#pragma unroll
    for (int off = 1; off < 16; off <<= 1)
#pragma unroll
      for (int r = 0; r < 4; ++r) tsum[r] += __shfl_xor(tsum[r], off, 64);
#pragma unroll
    for (int r = 0; r < 4; ++r) lrow[r] = lrow[r] * alpha[r] + tsum[r];
#pragma unroll
    for (int i = 0; i < 16; ++i)
#pragma unroll
      for (int r = 0; r < 4; ++r) oacc[i][r] *= alpha[r];

    // P relayout (wave-private LDS region, no barrier)
#pragma unroll
    for (int nt = 0; nt < 2; ++nt)
#pragma unroll
      for (int r = 0; r < 4; ++r)
        sh[16384 + w*640 + (lh*4 + r)*40 + nt*16 + lr] = f2bf(p[nt][r]);
    bf16x8 pfr = *(const bf16x8*)&sh[16384 + w*640 + lr*40 + lh*8];

    // ---- PV ----
    if (nx) { VMCNT4; } else { VMCNT0; }   // V[j] resident
    SBAR; SCHED0;
    __builtin_amdgcn_s_setprio(1);
#pragma unroll
    for (int dt = 0; dt < 16; ++dt) {
      bf16x8 vf = *(const bf16x8*)&sh[8192 + (dt*16 + lr)*32 + ((lh ^ fv) * 8)];
      oacc[dt] = __builtin_amdgcn_mfma_f32_16x16x32_bf16(pfr, vf, oacc[dt], 0, 0, 0);
    }
    __builtin_amdgcn_s_setprio(0);
    LGKM0; SBAR; SCHED0;
    if (nx) {        // restage V for j+1
      const unsigned short* vj = vbase + (size_t)(j + 1) * 32;
#pragma unroll
      for (int it = 0; it < 4; ++it) gld16(vj + voff[it], &sh[8192 + (it*256 + t) * 8]);
    }
  }

  // epilogue: O[b][s][h][d] bf16
  const int b = bh >> 4, h = bh & 15;
  float inv[4];
#pragma unroll
  for (int r = 0; r < 4; ++r) inv[r] = 1.f / lrow[r];
#pragma unroll
  for (int dt = 0; dt < 16; ++dt)
#pragma unroll
    for (int r = 0; r < 4; ++r) {
      int s = q0 + w * 16 + lh * 4 + r;
      O[((size_t)(b * TS + s) * TH + h) * THD + dt * 16 + lr] = f2bf(oacc[dt][r] * inv[r]);
    }
}

// ---------------- launch ----------------
extern "C" void kernel_launch(void* const* d_in, const int* in_sizes, int n_in,
                              void* d_out, int out_size, void* d_ws, size_t ws_size,
                              hipStream_t stream) {
  const float* hs   = (const float*)d_in[0];
  const float* sinp = (const float*)d_in[1];
  const float* cosp = (const float*)d_in[2];
  const float* Wq   = (const float*)d_in[3];
  const float* Wk   = (const float*)d_in[4];
  const float* Wv   = (const float*)d_in[5];
  const float* Wo   = (const float*)d_in[6];

  const size_t NE = (size_t)TM * TD;
  const size_t BYTES = NE * 2;
  char* ws = (char*)d_ws;
  unsigned short* hsb = (unsigned short*)(ws + 0*BYTES);
  unsigned short* Wqb = (unsigned short*)(ws + 1*BYTES);
  unsigned short* Wkb = (unsigned short*)(ws + 2*BYTES);
  unsigned short* Wvb = (unsigned short*)(ws + 3*BYTES);
  unsigned short* Wob = (unsigned short*)(ws + 4*BYTES);
  unsigned short* Qt  = (unsigned short*)(ws + 5*BYTES);  // [B,H,S,HD]
  unsigned short* Ktb = (unsigned short*)(ws + 6*BYTES);  // [B,H,S,HD]
  unsigned short* Vtb = (unsigned short*)(ws + 7*BYTES);  // [B,H,HD,S]
  unsigned short* Ob  = (unsigned short*)(ws + 8*BYTES);  // [B,S,H,HD] == [M,D]

  int n4 = (int)(NE / 4);
  int cvb = (n4 + 255) / 256;
  k_cvt<<<cvb, 256, 0, stream>>>(hs, hsb, n4);
  k_cvt<<<cvb, 256, 0, stream>>>(Wq, Wqb, n4);
  k_cvt<<<cvb, 256, 0, stream>>>(Wk, Wkb, n4);
  k_cvt<<<cvb, 256, 0, stream>>>(Wv, Wvb, n4);
  k_cvt<<<cvb, 256, 0, stream>>>(Wo, Wob, n4);

  k_gemm<1><<<256, 512, 0, stream>>>(hsb, Wqb, (void*)Qt,  sinp, cosp);
  k_gemm<1><<<256, 512, 0, stream>>>(hsb, Wkb, (void*)Ktb, sinp, cosp);
  k_gemm<2><<<256, 512, 0, stream>>>(hsb, Wvb, (void*)Vtb, nullptr, nullptr);

  k_fattn<<<dim3(TB*TH, TS/64), 256, 0, stream>>>(Qt, Ktb, Vtb, Ob);

  k_gemm<0><<<256, 512, 0, stream>>>(Ob, Wob, d_out, nullptr, nullptr);
}

// Round 5
// 817.530 us; speedup vs baseline: 1.6971x; 1.0610x over previous
//
#include <hip/hip_runtime.h>
#include <cstdint>
#include <cstddef>

#define TB 2
#define TS 2048
#define TD 4096
#define TH 16
#define THD 256
#define TROT 64
#define TM (TB*TS)

typedef __attribute__((ext_vector_type(8))) short bf16x8;
typedef __attribute__((ext_vector_type(4))) float f32x4;

#define LGKM0  asm volatile("s_waitcnt lgkmcnt(0)" ::: "memory")
#define VMCNT8 asm volatile("s_waitcnt vmcnt(8)" ::: "memory")
#define VMCNT4 asm volatile("s_waitcnt vmcnt(4)" ::: "memory")
#define VMCNT0 asm volatile("s_waitcnt vmcnt(0)" ::: "memory")
#define SBAR   __builtin_amdgcn_s_barrier()
#define SCHED0 __builtin_amdgcn_sched_barrier(0)

__device__ __forceinline__ unsigned short f2bf(float f) {
  union { float f; unsigned u; } v; v.f = f;
  return (unsigned short)((v.u + 0x7fffu + ((v.u >> 16) & 1u)) >> 16);
}

__device__ __forceinline__ void gld16(const void* g, void* l) {
  __builtin_amdgcn_global_load_lds(
      (const __attribute__((address_space(1))) unsigned int*)g,
      (__attribute__((address_space(3))) unsigned int*)l, 16, 0, 0);
}

// ---------------- fused fp32 -> bf16 convert (5 tensors, dst contiguous) ----
__global__ __launch_bounds__(256) void k_cvt5(
    const float* __restrict__ s0, const float* __restrict__ s1,
    const float* __restrict__ s2, const float* __restrict__ s3,
    const float* __restrict__ s4, unsigned short* __restrict__ dst) {
  int i = blockIdx.x * 256 + threadIdx.x;          // 5 * 2^22 chunks of 4 floats
  int tsel = i >> 22, il = i & 4194303;
  const float* s = tsel == 0 ? s0 : tsel == 1 ? s1 : tsel == 2 ? s2 : tsel == 3 ? s3 : s4;
  float4 v = reinterpret_cast<const float4*>(s)[il];
  ushort4 o;
  o.x = f2bf(v.x); o.y = f2bf(v.y); o.z = f2bf(v.z); o.w = f2bf(v.w);
  *reinterpret_cast<ushort4*>(dst + (size_t)i * 4) = o;
}

// ---------------- GEMM 256x256, BK=32, 8 waves, 4-phase, dbuf ----------------
// LDS subtiled [16][32] shorts; swizzle: col-chunk ^= (row>>1)&3 (2-way free).
// MODE 0: fp32 out [M,N]; MODE 1: RoPE+transpose -> bf16 [B,H,S,HD];
// MODE 2: V^T -> bf16 [B,H,HD,S] via LDS-bounce transpose.
template<int MODE>
__global__ __launch_bounds__(512, 2) void k_gemm(
    const unsigned short* __restrict__ A, const unsigned short* __restrict__ W,
    void* __restrict__ out, const float* __restrict__ sinp, const float* __restrict__ cosp)
{
  __shared__ unsigned short lds[32768];   // 64KB
  const int K = TD;
  const int t = threadIdx.x;
  const int w = t >> 6, l = t & 63, lr = l & 15, lh = l >> 4;
  const int wr = w >> 2, wc = w & 3;      // 2 x 4 waves; wave block 128x64

  // XCD swizzle (256 blocks = 8 XCD x 32, bijective)
  const int id = blockIdx.x;
  const int swz = (id & 7) * 32 + (id >> 3);
  const int m0 = (swz >> 4) * 256, n0 = (swz & 15) * 256;

  // per-lane LDS read offset within a [16][32] subtile: chunk = lh ^ ((row>>1)&3)
  const int llo = lr * 32 + ((lh ^ ((lr >> 1) & 3)) * 8);

  // staging source: chunk c -> row (c>>2)&15, LDS chunk-pos c&3 holds
  // global chunk (c&3) ^ ((row>>1)&3)   [involution with the read swizzle]
  size_t offA[2], offB[2];
#pragma unroll
  for (int it = 0; it < 2; ++it) {
    int c = it * 512 + t;
    int row = (c >> 6) * 16 + ((c >> 2) & 15);
    int cch = (c & 3) ^ ((c >> 3) & 3);
    offA[it] = (size_t)(m0 + row) * K + cch * 8;
    offB[it] = (size_t)(n0 + row) * K + cch * 8;
  }

  f32x4 acc[8][4];
#pragma unroll
  for (int i = 0; i < 8; ++i)
#pragma unroll
    for (int j = 0; j < 4; ++j) acc[i][j] = 0.f;

  // prologue: stage tiles 0 (buf0) and 1 (buf1)
  gld16(W + offB[0], &lds[8192 + t*8]);
  gld16(W + offB[1], &lds[8192 + (512+t)*8]);
  gld16(A + offA[0], &lds[t*8]);
  gld16(A + offA[1], &lds[(512+t)*8]);
  gld16(W + offB[0] + 32, &lds[16384 + 8192 + t*8]);
  gld16(W + offB[1] + 32, &lds[16384 + 8192 + (512+t)*8]);
  gld16(A + offA[0] + 32, &lds[16384 + t*8]);
  gld16(A + offA[1] + 32, &lds[16384 + (512+t)*8]);
  VMCNT4;
  SBAR;
  SCHED0;

  const int abase = wr * 8 * 512;
  const int bbase = 8192 + wc * 4 * 512;

  for (int i2 = 0; i2 < 64; ++i2) {
    const bool pf = (i2 < 63);
    const int ke2 = (i2 + 1) * 64;
    bf16x8 af[4], bfr[4];

    // ---- phase 1: buf0, m0-3 ----
#pragma unroll
    for (int n = 0; n < 4; ++n)  bfr[n] = *(const bf16x8*)&lds[bbase + n*512 + llo];
#pragma unroll
    for (int mi = 0; mi < 4; ++mi) af[mi] = *(const bf16x8*)&lds[abase + mi*512 + llo];
    LGKM0; SBAR; SCHED0;
    if (pf) {
      gld16(W + offB[0] + ke2, &lds[8192 + t*8]);
      gld16(W + offB[1] + ke2, &lds[8192 + (512+t)*8]);
    }
    __builtin_amdgcn_s_setprio(1);
#pragma unroll
    for (int mi = 0; mi < 4; ++mi)
#pragma unroll
      for (int n = 0; n < 4; ++n)
        acc[mi][n] = __builtin_amdgcn_mfma_f32_16x16x32_bf16(af[mi], bfr[n], acc[mi][n], 0,0,0);
    __builtin_amdgcn_s_setprio(0);
    SBAR;

    // ---- phase 2: buf0, m4-7 ----
#pragma unroll
    for (int mi = 0; mi < 4; ++mi) af[mi] = *(const bf16x8*)&lds[abase + (4+mi)*512 + llo];
    LGKM0; SBAR; SCHED0;
    if (pf) {
      gld16(A + offA[0] + ke2, &lds[t*8]);
      gld16(A + offA[1] + ke2, &lds[(512+t)*8]);
    }
    __builtin_amdgcn_s_setprio(1);
#pragma unroll
    for (int mi = 0; mi < 4; ++mi)
#pragma unroll
      for (int n = 0; n < 4; ++n)
        acc[4+mi][n] = __builtin_amdgcn_mfma_f32_16x16x32_bf16(af[mi], bfr[n], acc[4+mi][n], 0,0,0);
    __builtin_amdgcn_s_setprio(0);
    if (pf) { VMCNT4; } else { VMCNT0; }
    SBAR; SCHED0;

    // ---- phase 3: buf1, m0-3 ----
#pragma unroll
    for (int n = 0; n < 4; ++n)  bfr[n] = *(const bf16x8*)&lds[16384 + bbase + n*512 + llo];
#pragma unroll
    for (int mi = 0; mi < 4; ++mi) af[mi] = *(const bf16x8*)&lds[16384 + abase + mi*512 + llo];
    LGKM0; SBAR; SCHED0;
    if (pf) {
      gld16(W + offB[0] + ke2 + 32, &lds[16384 + 8192 + t*8]);
      gld16(W + offB[1] + ke2 + 32, &lds[16384 + 8192 + (512+t)*8]);
    }
    __builtin_amdgcn_s_setprio(1);
#pragma unroll
    for (int mi = 0; mi < 4; ++mi)
#pragma unroll
      for (int n = 0; n < 4; ++n)
        acc[mi][n] = __builtin_amdgcn_mfma_f32_16x16x32_bf16(af[mi], bfr[n], acc[mi][n], 0,0,0);
    __builtin_amdgcn_s_setprio(0);
    SBAR;

    // ---- phase 4: buf1, m4-7 ----
#pragma unroll
    for (int mi = 0; mi < 4; ++mi) af[mi] = *(const bf16x8*)&lds[16384 + abase + (4+mi)*512 + llo];
    LGKM0; SBAR; SCHED0;
    if (pf) {
      gld16(A + offA[0] + ke2 + 32, &lds[16384 + t*8]);
      gld16(A + offA[1] + ke2 + 32, &lds[16384 + (512+t)*8]);
    }
    __builtin_amdgcn_s_setprio(1);
#pragma unroll
    for (int mi = 0; mi < 4; ++mi)
#pragma unroll
      for (int n = 0; n < 4; ++n)
        acc[4+mi][n] = __builtin_amdgcn_mfma_f32_16x16x32_bf16(af[mi], bfr[n], acc[4+mi][n], 0,0,0);
    __builtin_amdgcn_s_setprio(0);
    if (pf) { VMCNT4; } else { VMCNT0; }
    SBAR; SCHED0;
  }

  // -------- epilogues --------
  if constexpr (MODE == 2) {
    const int b = m0 >> 11, sbase = m0 & (TS - 1);
#pragma unroll
    for (int p = 0; p < 4; ++p) {
      __syncthreads();
      if (wc == p) {
#pragma unroll
        for (int m = 0; m < 8; ++m)
#pragma unroll
          for (int n = 0; n < 4; ++n) {
            int lcol = n * 16 + lr;
            int srow = wr * 128 + m * 16 + lh * 4;
            ushort4 o;
            o.x = f2bf(acc[m][n][0]); o.y = f2bf(acc[m][n][1]);
            o.z = f2bf(acc[m][n][2]); o.w = f2bf(acc[m][n][3]);
            *(ushort4*)&lds[lcol * 280 + srow] = o;
          }
      }
      __syncthreads();
#pragma unroll
      for (int i = 0; i < 4; ++i) {
        int q = i * 512 + t;
        int dl = q >> 5, sc = q & 31;
        uint4 v = *(const uint4*)&lds[dl * 280 + sc * 8];
        int d = n0 + p * 64 + dl;
        *(uint4*)((unsigned short*)out +
                  ((size_t)((b * TH + (d >> 8)) * THD + (d & 255))) * TS + sbase + sc * 8) = v;
      }
    }
  } else {
#pragma unroll
    for (int m = 0; m < 8; ++m)
#pragma unroll
      for (int n = 0; n < 4; ++n)
#pragma unroll
        for (int r = 0; r < 4; ++r) {
          int row = m0 + wr * 128 + m * 16 + lh * 4 + r;
          int col = n0 + wc * 64 + n * 16 + lr;
          float x = acc[m][n][r];
          if constexpr (MODE == 0) {
            ((float*)out)[(size_t)row * TD + col] = x;
          } else {
            float part = __shfl_xor(x, 1, 64);
            int s = row & (TS - 1), b = row >> 11;
            int h = col >> 8, d = col & 255;
            float val = x;
            if (d < TROT) {
              float cc = cosp[s * TROT + d], ss = sinp[s * TROT + d];
              val = x * cc + ((d & 1) ? part : -part) * ss;
            }
            ((unsigned short*)out)[((size_t)(b * TH + h) * TS + s) * THD + d] = f2bf(val);
          }
        }
  }
}

// ---------------- causal flash attention, KVBLK=64 ----------------
// Qt,Kt: [B,H,S,HD] bf16.  Vt: [B,H,HD,S] bf16.  O: [B,S,H,HD] bf16.
// 4 waves; wave w owns q rows [q0+16w,+16). gld16 staging, staggered K/V,
// counted vmcnt(8), defer-max (T13, THR=8). Dynamic LDS 74752 B.
__global__ __launch_bounds__(256, 2) void k_fattn(
    const unsigned short* __restrict__ Qt, const unsigned short* __restrict__ Kt,
    const unsigned short* __restrict__ Vt, unsigned short* __restrict__ O)
{
  extern __shared__ unsigned short sh[];   // K 32KB | V 32KB | Ps 9KB
  const int t = threadIdx.x, w = t >> 6, l = t & 63, lr = l & 15, lh = l >> 4;
  const int bh = blockIdx.x;
  const int qb = (gridDim.y - 1) - blockIdx.y;   // LPT: heaviest first
  const int q0 = qb * 64;
  const int jmax = qb;

  const unsigned short* kbase = Kt + (size_t)bh * TS * THD;
  const unsigned short* vbase = Vt + (size_t)bh * THD * TS;

  const int llo = lr * 32 + ((lh ^ ((lr >> 1) & 3)) * 8);

  // staging source offsets (chunk c = it*256 + t); LDS dest = c*16 B (linear)
  int koff[8], voff[8];
#pragma unroll
  for (int it = 0; it < 8; ++it) {
    int c = it * 256 + t;
    int row = (c >> 2) & 15;
    int scc = (c & 3) ^ ((row >> 1) & 3);
    koff[it] = (((c >> 9) & 3) * 16 + row) * THD + ((c >> 6) & 7) * 32 + scc * 8;
    voff[it] = (((c >> 6) & 15) * 16 + row) * TS + ((c >> 10) & 1) * 32 + scc * 8;
  }

  bf16x8 qf[8];
  const unsigned short* qp = Qt + ((size_t)bh * TS + q0 + w * 16 + lr) * THD;
#pragma unroll
  for (int kk = 0; kk < 8; ++kk) qf[kk] = *(const bf16x8*)(qp + kk * 32 + lh * 8);

  f32x4 oacc[16];
#pragma unroll
  for (int i = 0; i < 16; ++i) oacc[i] = 0.f;
  float mrow[4] = {-__builtin_inff(), -__builtin_inff(), -__builtin_inff(), -__builtin_inff()};
  float lrow[4] = {0.f, 0.f, 0.f, 0.f};

  // prologue: stage K[0] then V[0]
#pragma unroll
  for (int it = 0; it < 8; ++it) gld16(kbase + koff[it], &sh[(it*256 + t) * 8]);
#pragma unroll
  for (int it = 0; it < 8; ++it) gld16(vbase + voff[it], &sh[16384 + (it*256 + t) * 8]);

  for (int j = 0; j <= jmax; ++j) {
    const bool nx = (j < jmax);
    VMCNT8; SBAR; SCHED0;      // K[j] resident wave-locally; barrier -> globally

    // ---- QK^T : 32 MFMA ----
    f32x4 sacc[4];
#pragma unroll
    for (int nt = 0; nt < 4; ++nt) sacc[nt] = 0.f;
    __builtin_amdgcn_s_setprio(1);
#pragma unroll
    for (int nt = 0; nt < 4; ++nt)
#pragma unroll
      for (int kk = 0; kk < 8; ++kk) {
        bf16x8 kf = *(const bf16x8*)&sh[(nt*8 + kk)*512 + llo];
        sacc[nt] = __builtin_amdgcn_mfma_f32_16x16x32_bf16(qf[kk], kf, sacc[nt], 0, 0, 0);
      }
    __builtin_amdgcn_s_setprio(0);
    LGKM0; SBAR; SCHED0;
    if (nx) {                  // restage K for j+1 under softmax+PV
      const unsigned short* kj = kbase + (size_t)(j + 1) * 64 * THD;
#pragma unroll
      for (int it = 0; it < 8; ++it) gld16(kj + koff[it], &sh[(it*256 + t) * 8]);
    }

    // ---- online softmax ----
    float p[4][4], tmax[4];
    const int qrow0 = q0 + w * 16 + lh * 4;
#pragma unroll
    for (int r = 0; r < 4; ++r) tmax[r] = -__builtin_inff();
#pragma unroll
    for (int nt = 0; nt < 4; ++nt) {
      int kpos = j * 64 + nt * 16 + lr;
#pragma unroll
      for (int r = 0; r < 4; ++r) {
        float sv = sacc[nt][r] * 0.0625f;
        if (kpos > qrow0 + r) sv = -__builtin_inff();
        p[nt][r] = sv;
        tmax[r] = fmaxf(tmax[r], sv);
      }
    }
#pragma unroll
    for (int off = 1; off < 16; off <<= 1)
#pragma unroll
      for (int r = 0; r < 4; ++r) tmax[r] = fmaxf(tmax[r], __shfl_xor(tmax[r], off, 64));

    // defer-max: rescale only when a row max grew by > 8
    float g = fmaxf(fmaxf(tmax[0] - mrow[0], tmax[1] - mrow[1]),
                    fmaxf(tmax[2] - mrow[2], tmax[3] - mrow[3]));
    if (__any(g > 8.f)) {
      float alpha[4];
#pragma unroll
      for (int r = 0; r < 4; ++r) {
        float mn = fmaxf(mrow[r], tmax[r]);
        alpha[r] = __expf(mrow[r] - mn);
        mrow[r] = mn;
        lrow[r] *= alpha[r];
      }
#pragma unroll
      for (int i = 0; i < 16; ++i)
#pragma unroll
        for (int r = 0; r < 4; ++r) oacc[i][r] *= alpha[r];
    }

    float tsum[4] = {0.f, 0.f, 0.f, 0.f};
#pragma unroll
    for (int nt = 0; nt < 4; ++nt)
#pragma unroll
      for (int r = 0; r < 4; ++r) {
        float pe = __expf(p[nt][r] - mrow[r]);   // bounded by e^8
        p[nt][r] = pe;
        tsum[r] += pe;
      }
#pragma unroll
    for (int off = 1; off < 16; off <<= 1)
#pragma unroll
      for (int r = 0; r < 4; ++r) tsum[r] += __shfl_xor(tsum[r], off, 64);
#pragma unroll
    for (int r = 0; r < 4; ++r) lrow[r] += tsum[r];

    // P relayout (wave-private LDS region): C layout -> two A-fragments
    const int wb = 32768 + w * 1152;             // stride 72 shorts
#pragma unroll
    for (int nt = 0; nt < 4; ++nt)
#pragma unroll
      for (int r = 0; r < 4; ++r)
        sh[wb + (lh*4 + r)*72 + nt*16 + lr] = f2bf(p[nt][r]);
    bf16x8 pfr0 = *(const bf16x8*)&sh[wb + lr*72 + lh*8];
    bf16x8 pfr1 = *(const bf16x8*)&sh[wb + lr*72 + 32 + lh*8];

    // ---- PV : 32 MFMA ----
    if (nx) { VMCNT8; } else { VMCNT0; }         // V[j] resident
    SBAR; SCHED0;
    __builtin_amdgcn_s_setprio(1);
#pragma unroll
    for (int dt = 0; dt < 16; ++dt) {
      bf16x8 vf = *(const bf16x8*)&sh[16384 + dt*512 + llo];
      oacc[dt] = __builtin_amdgcn_mfma_f32_16x16x32_bf16(pfr0, vf, oacc[dt], 0, 0, 0);
    }
#pragma unroll
    for (int dt = 0; dt < 16; ++dt) {
      bf16x8 vf = *(const bf16x8*)&sh[16384 + (16 + dt)*512 + llo];
      oacc[dt] = __builtin_amdgcn_mfma_f32_16x16x32_bf16(pfr1, vf, oacc[dt], 0, 0, 0);
    }
    __builtin_amdgcn_s_setprio(0);
    LGKM0; SBAR; SCHED0;
    if (nx) {                  // restage V for j+1
      const unsigned short* vj = vbase + (size_t)(j + 1) * 64;
#pragma unroll
      for (int it = 0; it < 8; ++it) gld16(vj + voff[it], &sh[16384 + (it*256 + t) * 8]);
    }
  }

  // epilogue: O[b][s][h][d] bf16
  const int b = bh >> 4, h = bh & 15;
  float inv[4];
#pragma unroll
  for (int r = 0; r < 4; ++r) inv[r] = 1.f / lrow[r];
#pragma unroll
  for (int dt = 0; dt < 16; ++dt)
#pragma unroll
    for (int r = 0; r < 4; ++r) {
      int s = q0 + w * 16 + lh * 4 + r;
      O[((size_t)(b * TS + s) * TH + h) * THD + dt * 16 + lr] = f2bf(oacc[dt][r] * inv[r]);
    }
}

// ---------------- launch ----------------
extern "C" void kernel_launch(void* const* d_in, const int* in_sizes, int n_in,
                              void* d_out, int out_size, void* d_ws, size_t ws_size,
                              hipStream_t stream) {
  const float* hs   = (const float*)d_in[0];
  const float* sinp = (const float*)d_in[1];
  const float* cosp = (const float*)d_in[2];
  const float* Wq   = (const float*)d_in[3];
  const float* Wk   = (const float*)d_in[4];
  const float* Wv   = (const float*)d_in[5];
  const float* Wo   = (const float*)d_in[6];

  const size_t NE = (size_t)TM * TD;
  const size_t BYTES = NE * 2;
  char* ws = (char*)d_ws;
  unsigned short* hsb = (unsigned short*)(ws + 0*BYTES);
  unsigned short* Wqb = (unsigned short*)(ws + 1*BYTES);
  unsigned short* Wkb = (unsigned short*)(ws + 2*BYTES);
  unsigned short* Wvb = (unsigned short*)(ws + 3*BYTES);
  unsigned short* Wob = (unsigned short*)(ws + 4*BYTES);
  unsigned short* Qt  = (unsigned short*)(ws + 5*BYTES);  // [B,H,S,HD]
  unsigned short* Ktb = (unsigned short*)(ws + 6*BYTES);  // [B,H,S,HD]
  unsigned short* Vtb = (unsigned short*)(ws + 7*BYTES);  // [B,H,HD,S]
  unsigned short* Ob  = (unsigned short*)(ws + 8*BYTES);  // [B,S,H,HD] == [M,D]

  // fused convert: 5 * NE/4 chunks = 81920 blocks
  k_cvt5<<<81920, 256, 0, stream>>>(hs, Wq, Wk, Wv, Wo, hsb);

  k_gemm<1><<<256, 512, 0, stream>>>(hsb, Wqb, (void*)Qt,  sinp, cosp);
  k_gemm<1><<<256, 512, 0, stream>>>(hsb, Wkb, (void*)Ktb, sinp, cosp);
  k_gemm<2><<<256, 512, 0, stream>>>(hsb, Wvb, (void*)Vtb, nullptr, nullptr);

  k_fattn<<<dim3(TB*TH, TS/64), 256, 74752, stream>>>(Qt, Ktb, Vtb, Ob);

  k_gemm<0><<<256, 512, 0, stream>>>(Ob, Wob, d_out, nullptr, nullptr);
}

// Round 6
// 757.328 us; speedup vs baseline: 1.8320x; 1.0795x over previous
//
#include <hip/hip_runtime.h>
#include <cstdint>
#include <cstddef>

#define TB 2
#define TS 2048
#define TD 4096
#define TH 16
#define THD 256
#define TROT 64
#define TM (TB*TS)

typedef __attribute__((ext_vector_type(8))) short bf16x8;
typedef __attribute__((ext_vector_type(4))) float f32x4;

#define LGKM0  asm volatile("s_waitcnt lgkmcnt(0)" ::: "memory")
#define VMCNT8 asm volatile("s_waitcnt vmcnt(8)" ::: "memory")
#define VMCNT0 asm volatile("s_waitcnt vmcnt(0)" ::: "memory")
#define SBAR   __builtin_amdgcn_s_barrier()
#define SCHED0 __builtin_amdgcn_sched_barrier(0)

__device__ __forceinline__ unsigned short f2bf(float f) {
  union { float f; unsigned u; } v; v.f = f;
  return (unsigned short)((v.u + 0x7fffu + ((v.u >> 16) & 1u)) >> 16);
}

__device__ __forceinline__ void gld16(const void* g, void* l) {
  __builtin_amdgcn_global_load_lds(
      (const __attribute__((address_space(1))) unsigned int*)g,
      (__attribute__((address_space(3))) unsigned int*)l, 16, 0, 0);
}

// ---------------- fused fp32 -> bf16 convert (5 tensors, dst contiguous) ----
__global__ __launch_bounds__(256) void k_cvt5(
    const float* __restrict__ s0, const float* __restrict__ s1,
    const float* __restrict__ s2, const float* __restrict__ s3,
    const float* __restrict__ s4, unsigned short* __restrict__ dst) {
  int i = blockIdx.x * 256 + threadIdx.x;          // 5 * 2^22 chunks of 4 floats
  int tsel = i >> 22, il = i & 4194303;
  const float* s = tsel == 0 ? s0 : tsel == 1 ? s1 : tsel == 2 ? s2 : tsel == 3 ? s3 : s4;
  float4 v = reinterpret_cast<const float4*>(s)[il];
  ushort4 o;
  o.x = f2bf(v.x); o.y = f2bf(v.y); o.z = f2bf(v.z); o.w = f2bf(v.w);
  *reinterpret_cast<ushort4*>(dst + (size_t)i * 4) = o;
}

// ---------------- GEMM 256x256, BK=64, 8 waves, true 8-phase (m201) --------
// Per phase: all 8 waves compute one 128x128 C-quadrant (qa,qb); wave slice
// 64x32 = 4m x 2n frags x 2kk = 16 MFMA. Each phase stages ONE half-tile
// (128 rows x 64 k of A or B) via 2 gld16/thread; counted vmcnt (never 0).
// LDS 128 KiB: [buf][A|B][half(128x64)] ; subtile [16][32] swizzled.
// MODE 0: fp32 out [M,N]; MODE 1: RoPE+transpose -> bf16 [B,H,S,HD];
// MODE 2: V^T -> bf16 [B,H,HD,S] via LDS-bounce transpose.
template<int MODE>
__global__ __launch_bounds__(512, 1) void k_gemm(
    const unsigned short* __restrict__ A, const unsigned short* __restrict__ W,
    void* __restrict__ out, const float* __restrict__ sinp, const float* __restrict__ cosp)
{
  extern __shared__ unsigned short lds[];   // 131072 B
  const int K = TD;
  const int t = threadIdx.x;
  const int w = t >> 6, l = t & 63, lr = l & 15, lh = l >> 4;
  const int wm = w >> 2, wn = w & 3;        // 2 x 4 waves within quadrant

  // XCD swizzle (256 blocks = 8 XCD x 32, bijective)
  const int id = blockIdx.x;
  const int swz = (id & 7) * 32 + (id >> 3);
  const int m0 = (swz >> 4) * 256, n0 = (swz & 15) * 256;

  // per-lane LDS read offset within [16][32] subtile: chunk = lh ^ ((row>>1)&3)
  const int llo = lr * 32 + ((lh ^ ((lr >> 1) & 3)) * 8);

  const unsigned short* srcA = A + (size_t)m0 * K;
  const unsigned short* srcB = W + (size_t)n0 * K;

  // staging source offsets (k-invariant part); chunk c = it*512 + t
  int roff[2];
#pragma unroll
  for (int it = 0; it < 2; ++it) {
    int c = it * 512 + t;
    int rl = (c >> 2) & 15;
    roff[it] = (16 * (c >> 7) + rl) * K + ((c >> 6) & 1) * 32 + ((c & 3) ^ ((rl >> 1) & 3)) * 8;
  }

  f32x4 acc[2][2][4][2];    // [qa][qb][m][n]
#pragma unroll
  for (int qa = 0; qa < 2; ++qa)
#pragma unroll
    for (int qb = 0; qb < 2; ++qb)
#pragma unroll
      for (int m = 0; m < 4; ++m)
#pragma unroll
        for (int n = 0; n < 2; ++n) acc[qa][qb][m][n] = 0.f;

  bf16x8 af[4][2], bfv[2][2];

#define STG(SBUF, SAB, SHALF, SKOFS) { \
    const unsigned short* _s = (SAB) ? srcB : srcA; \
    const int _b = (SBUF)*32768 + (SAB)*16384 + (SHALF)*8192; \
    gld16(_s + (size_t)(SHALF)*128*TD + (SKOFS) + roff[0], &lds[_b + t*8]); \
    gld16(_s + (size_t)(SHALF)*128*TD + (SKOFS) + roff[1], &lds[_b + (512+t)*8]); }

#define PHASE(BUF, QA, QB, DOAF, SBUF, SAB, SHALF, SKOFS, VMN) { \
    if (DOAF) { \
      _Pragma("unroll") for (int m = 0; m < 4; ++m) \
      _Pragma("unroll") for (int kk = 0; kk < 2; ++kk) \
        af[m][kk] = *(const bf16x8*)&lds[(BUF)*32768 + (QA)*8192 + ((wm*4+m)*2+kk)*512 + llo]; \
    } \
    _Pragma("unroll") for (int n = 0; n < 2; ++n) \
    _Pragma("unroll") for (int kk = 0; kk < 2; ++kk) \
      bfv[n][kk] = *(const bf16x8*)&lds[(BUF)*32768 + 16384 + (QB)*8192 + ((wn*2+n)*2+kk)*512 + llo]; \
    LGKM0; SBAR; SCHED0; \
    STG(SBUF, SAB, SHALF, SKOFS); \
    asm volatile("s_waitcnt vmcnt(" #VMN ")" ::: "memory"); \
    __builtin_amdgcn_s_setprio(1); \
    _Pragma("unroll") for (int m = 0; m < 4; ++m) \
    _Pragma("unroll") for (int n = 0; n < 2; ++n) \
    _Pragma("unroll") for (int kk = 0; kk < 2; ++kk) \
      acc[QA][QB][m][n] = __builtin_amdgcn_mfma_f32_16x16x32_bf16(af[m][kk], bfv[n][kk], acc[QA][QB][m][n], 0,0,0); \
    __builtin_amdgcn_s_setprio(0); \
    SBAR; SCHED0; }

  const int NT = K / 64;      // 64 K-tiles

  // prologue: b0 fully (tau=0), b1 A.h0/B.h0 (tau=1); b1 h1 staged by P1/P2
  STG(0,0,0, 0);  SCHED0;
  STG(0,1,0, 0);  SCHED0;
  STG(0,0,1, 0);  SCHED0;
  STG(0,1,1, 0);  SCHED0;
  STG(1,0,0, 64); SCHED0;
  STG(1,1,0, 64); SCHED0;
  VMCNT8; SBAR; SCHED0;

  for (int i2 = 0; i2 < NT/2; ++i2) {
    const int k1c = (2*i2+1) * 64;
    const int k0n = (2*i2+2 < NT ? 2*i2+2 : NT-1) * 64;
    const int k1n = (2*i2+3 < NT ? 2*i2+3 : NT-1) * 64;
    PHASE(0, 0,0, 1,  1,0,1, k1c, 6);   // stage b1.A.h1 <- tau1
    PHASE(0, 0,1, 0,  1,1,1, k1c, 8);   // stage b1.B.h1 <- tau1
    PHASE(0, 1,0, 1,  0,0,0, k0n, 10);  // stage b0.A.h0 <- tau0+2
    PHASE(0, 1,1, 0,  0,1,0, k0n, 8);   // stage b0.B.h0
    PHASE(1, 0,0, 1,  0,0,1, k0n, 6);   // stage b0.A.h1
    PHASE(1, 0,1, 0,  0,1,1, k0n, 8);   // stage b0.B.h1
    PHASE(1, 1,0, 1,  1,0,0, k1n, 10);  // stage b1.A.h0 <- tau1+2
    PHASE(1, 1,1, 0,  1,1,0, k1n, 8);   // stage b1.B.h0
  }
#undef PHASE
#undef STG

  // -------- epilogues --------
  if constexpr (MODE == 2) {
    // V^T [B,H,HD,S]: 8 passes over (qb,n); slab [64 cols][256 rows] in LDS.
    VMCNT0; SBAR;
    const int b = m0 >> 11, sbase = m0 & (TS - 1);
#pragma unroll
    for (int qb = 0; qb < 2; ++qb)
#pragma unroll
      for (int n = 0; n < 2; ++n) {
        __syncthreads();
#pragma unroll
        for (int qa = 0; qa < 2; ++qa)
#pragma unroll
          for (int m = 0; m < 4; ++m) {
            int lcol = wn * 16 + lr;
            int srow = qa * 128 + wm * 64 + m * 16 + lh * 4;
            ushort4 o;
            o.x = f2bf(acc[qa][qb][m][n][0]); o.y = f2bf(acc[qa][qb][m][n][1]);
            o.z = f2bf(acc[qa][qb][m][n][2]); o.w = f2bf(acc[qa][qb][m][n][3]);
            *(ushort4*)&lds[lcol * 268 + srow] = o;
          }
        __syncthreads();
#pragma unroll
        for (int rr = 0; rr < 4; ++rr) {
          int idx = rr * 512 + t;              // 2048 chunks: 64 cols x 32 x 16B
          int dl = idx >> 5, sc = (idx & 31) * 8;
          uint4 v = *(const uint4*)&lds[dl * 268 + sc];
          int d = n0 + qb * 128 + (dl >> 4) * 32 + n * 16 + (dl & 15);
          *(uint4*)((unsigned short*)out +
                    ((size_t)((b * TH + (d >> 8)) * THD + (d & 255))) * TS + sbase + sc) = v;
        }
      }
  } else {
#pragma unroll
    for (int qa = 0; qa < 2; ++qa)
#pragma unroll
      for (int qb = 0; qb < 2; ++qb)
#pragma unroll
        for (int m = 0; m < 4; ++m)
#pragma unroll
          for (int n = 0; n < 2; ++n)
#pragma unroll
            for (int r = 0; r < 4; ++r) {
              int row = m0 + qa * 128 + wm * 64 + m * 16 + lh * 4 + r;
              int col = n0 + qb * 128 + wn * 32 + n * 16 + lr;
              float x = acc[qa][qb][m][n][r];
              if constexpr (MODE == 0) {
                ((float*)out)[(size_t)row * TD + col] = x;
              } else {
                float part = __shfl_xor(x, 1, 64);
                int s = row & (TS - 1), b = row >> 11;
                int h = col >> 8, d = col & 255;
                float val = x;
                if (d < TROT) {
                  float cc = cosp[s * TROT + d], ss = sinp[s * TROT + d];
                  val = x * cc + ((d & 1) ? part : -part) * ss;
                }
                ((unsigned short*)out)[((size_t)(b * TH + h) * TS + s) * THD + d] = f2bf(val);
              }
            }
  }
}

// ---------------- causal flash attention, KVBLK=64 (unchanged) -------------
__global__ __launch_bounds__(256, 2) void k_fattn(
    const unsigned short* __restrict__ Qt, const unsigned short* __restrict__ Kt,
    const unsigned short* __restrict__ Vt, unsigned short* __restrict__ O)
{
  extern __shared__ unsigned short sh[];   // K 32KB | V 32KB | Ps 9KB
  const int t = threadIdx.x, w = t >> 6, l = t & 63, lr = l & 15, lh = l >> 4;
  const int bh = blockIdx.x;
  const int qb = (gridDim.y - 1) - blockIdx.y;   // LPT: heaviest first
  const int q0 = qb * 64;
  const int jmax = qb;

  const unsigned short* kbase = Kt + (size_t)bh * TS * THD;
  const unsigned short* vbase = Vt + (size_t)bh * THD * TS;

  const int llo = lr * 32 + ((lh ^ ((lr >> 1) & 3)) * 8);

  int koff[8], voff[8];
#pragma unroll
  for (int it = 0; it < 8; ++it) {
    int c = it * 256 + t;
    int row = (c >> 2) & 15;
    int scc = (c & 3) ^ ((row >> 1) & 3);
    koff[it] = (((c >> 9) & 3) * 16 + row) * THD + ((c >> 6) & 7) * 32 + scc * 8;
    voff[it] = (((c >> 6) & 15) * 16 + row) * TS + ((c >> 10) & 1) * 32 + scc * 8;
  }

  bf16x8 qf[8];
  const unsigned short* qp = Qt + ((size_t)bh * TS + q0 + w * 16 + lr) * THD;
#pragma unroll
  for (int kk = 0; kk < 8; ++kk) qf[kk] = *(const bf16x8*)(qp + kk * 32 + lh * 8);

  f32x4 oacc[16];
#pragma unroll
  for (int i = 0; i < 16; ++i) oacc[i] = 0.f;
  float mrow[4] = {-__builtin_inff(), -__builtin_inff(), -__builtin_inff(), -__builtin_inff()};
  float lrow[4] = {0.f, 0.f, 0.f, 0.f};

#pragma unroll
  for (int it = 0; it < 8; ++it) gld16(kbase + koff[it], &sh[(it*256 + t) * 8]);
#pragma unroll
  for (int it = 0; it < 8; ++it) gld16(vbase + voff[it], &sh[16384 + (it*256 + t) * 8]);

  for (int j = 0; j <= jmax; ++j) {
    const bool nx = (j < jmax);
    VMCNT8; SBAR; SCHED0;

    f32x4 sacc[4];
#pragma unroll
    for (int nt = 0; nt < 4; ++nt) sacc[nt] = 0.f;
    __builtin_amdgcn_s_setprio(1);
#pragma unroll
    for (int nt = 0; nt < 4; ++nt)
#pragma unroll
      for (int kk = 0; kk < 8; ++kk) {
        bf16x8 kf = *(const bf16x8*)&sh[(nt*8 + kk)*512 + llo];
        sacc[nt] = __builtin_amdgcn_mfma_f32_16x16x32_bf16(qf[kk], kf, sacc[nt], 0, 0, 0);
      }
    __builtin_amdgcn_s_setprio(0);
    LGKM0; SBAR; SCHED0;
    if (nx) {
      const unsigned short* kj = kbase + (size_t)(j + 1) * 64 * THD;
#pragma unroll
      for (int it = 0; it < 8; ++it) gld16(kj + koff[it], &sh[(it*256 + t) * 8]);
    }

    float p[4][4], tmax[4];
    const int qrow0 = q0 + w * 16 + lh * 4;
#pragma unroll
    for (int r = 0; r < 4; ++r) tmax[r] = -__builtin_inff();
#pragma unroll
    for (int nt = 0; nt < 4; ++nt) {
      int kpos = j * 64 + nt * 16 + lr;
#pragma unroll
      for (int r = 0; r < 4; ++r) {
        float sv = sacc[nt][r] * 0.0625f;
        if (kpos > qrow0 + r) sv = -__builtin_inff();
        p[nt][r] = sv;
        tmax[r] = fmaxf(tmax[r], sv);
      }
    }
#pragma unroll
    for (int off = 1; off < 16; off <<= 1)
#pragma unroll
      for (int r = 0; r < 4; ++r) tmax[r] = fmaxf(tmax[r], __shfl_xor(tmax[r], off, 64));

    float g = fmaxf(fmaxf(tmax[0] - mrow[0], tmax[1] - mrow[1]),
                    fmaxf(tmax[2] - mrow[2], tmax[3] - mrow[3]));
    if (__any(g > 8.f)) {
      float alpha[4];
#pragma unroll
      for (int r = 0; r < 4; ++r) {
        float mn = fmaxf(mrow[r], tmax[r]);
        alpha[r] = __expf(mrow[r] - mn);
        mrow[r] = mn;
        lrow[r] *= alpha[r];
      }
#pragma unroll
      for (int i = 0; i < 16; ++i)
#pragma unroll
        for (int r = 0; r < 4; ++r) oacc[i][r] *= alpha[r];
    }

    float tsum[4] = {0.f, 0.f, 0.f, 0.f};
#pragma unroll
    for (int nt = 0; nt < 4; ++nt)
#pragma unroll
      for (int r = 0; r < 4; ++r) {
        float pe = __expf(p[nt][r] - mrow[r]);
        p[nt][r] = pe;
        tsum[r] += pe;
      }
#pragma unroll
    for (int off = 1; off < 16; off <<= 1)
#pragma unroll
      for (int r = 0; r < 4; ++r) tsum[r] += __shfl_xor(tsum[r], off, 64);
#pragma unroll
    for (int r = 0; r < 4; ++r) lrow[r] += tsum[r];

    const int wb = 32768 + w * 1152;
#pragma unroll
    for (int nt = 0; nt < 4; ++nt)
#pragma unroll
      for (int r = 0; r < 4; ++r)
        sh[wb + (lh*4 + r)*72 + nt*16 + lr] = f2bf(p[nt][r]);
    bf16x8 pfr0 = *(const bf16x8*)&sh[wb + lr*72 + lh*8];
    bf16x8 pfr1 = *(const bf16x8*)&sh[wb + lr*72 + 32 + lh*8];

    if (nx) { VMCNT8; } else { VMCNT0; }
    SBAR; SCHED0;
    __builtin_amdgcn_s_setprio(1);
#pragma unroll
    for (int dt = 0; dt < 16; ++dt) {
      bf16x8 vf = *(const bf16x8*)&sh[16384 + dt*512 + llo];
      oacc[dt] = __builtin_amdgcn_mfma_f32_16x16x32_bf16(pfr0, vf, oacc[dt], 0, 0, 0);
    }
#pragma unroll
    for (int dt = 0; dt < 16; ++dt) {
      bf16x8 vf = *(const bf16x8*)&sh[16384 + (16 + dt)*512 + llo];
      oacc[dt] = __builtin_amdgcn_mfma_f32_16x16x32_bf16(pfr1, vf, oacc[dt], 0, 0, 0);
    }
    __builtin_amdgcn_s_setprio(0);
    LGKM0; SBAR; SCHED0;
    if (nx) {
      const unsigned short* vj = vbase + (size_t)(j + 1) * 64;
#pragma unroll
      for (int it = 0; it < 8; ++it) gld16(vj + voff[it], &sh[16384 + (it*256 + t) * 8]);
    }
  }

  const int b = bh >> 4, h = bh & 15;
  float inv[4];
#pragma unroll
  for (int r = 0; r < 4; ++r) inv[r] = 1.f / lrow[r];
#pragma unroll
  for (int dt = 0; dt < 16; ++dt)
#pragma unroll
    for (int r = 0; r < 4; ++r) {
      int s = q0 + w * 16 + lh * 4 + r;
      O[((size_t)(b * TS + s) * TH + h) * THD + dt * 16 + lr] = f2bf(oacc[dt][r] * inv[r]);
    }
}

// ---------------- launch ----------------
extern "C" void kernel_launch(void* const* d_in, const int* in_sizes, int n_in,
                              void* d_out, int out_size, void* d_ws, size_t ws_size,
                              hipStream_t stream) {
  const float* hs   = (const float*)d_in[0];
  const float* sinp = (const float*)d_in[1];
  const float* cosp = (const float*)d_in[2];
  const float* Wq   = (const float*)d_in[3];
  const float* Wk   = (const float*)d_in[4];
  const float* Wv   = (const float*)d_in[5];
  const float* Wo   = (const float*)d_in[6];

  const size_t NE = (size_t)TM * TD;
  const size_t BYTES = NE * 2;
  char* ws = (char*)d_ws;
  unsigned short* hsb = (unsigned short*)(ws + 0*BYTES);
  unsigned short* Wqb = (unsigned short*)(ws + 1*BYTES);
  unsigned short* Wkb = (unsigned short*)(ws + 2*BYTES);
  unsigned short* Wvb = (unsigned short*)(ws + 3*BYTES);
  unsigned short* Wob = (unsigned short*)(ws + 4*BYTES);
  unsigned short* Qt  = (unsigned short*)(ws + 5*BYTES);  // [B,H,S,HD]
  unsigned short* Ktb = (unsigned short*)(ws + 6*BYTES);  // [B,H,S,HD]
  unsigned short* Vtb = (unsigned short*)(ws + 7*BYTES);  // [B,H,HD,S]
  unsigned short* Ob  = (unsigned short*)(ws + 8*BYTES);  // [B,S,H,HD] == [M,D]

  k_cvt5<<<81920, 256, 0, stream>>>(hs, Wq, Wk, Wv, Wo, hsb);

  k_gemm<1><<<256, 512, 131072, stream>>>(hsb, Wqb, (void*)Qt,  sinp, cosp);
  k_gemm<1><<<256, 512, 131072, stream>>>(hsb, Wkb, (void*)Ktb, sinp, cosp);
  k_gemm<2><<<256, 512, 131072, stream>>>(hsb, Wvb, (void*)Vtb, nullptr, nullptr);

  k_fattn<<<dim3(TB*TH, TS/64), 256, 74752, stream>>>(Qt, Ktb, Vtb, Ob);

  k_gemm<0><<<256, 512, 131072, stream>>>(Ob, Wob, d_out, nullptr, nullptr);
}

// Round 7
// 738.216 us; speedup vs baseline: 1.8794x; 1.0259x over previous
//
#include <hip/hip_runtime.h>
#include <cstdint>
#include <cstddef>

#define TB 2
#define TS 2048
#define TD 4096
#define TH 16
#define THD 256
#define TROT 64
#define TM (TB*TS)

typedef __attribute__((ext_vector_type(8))) short bf16x8;
typedef __attribute__((ext_vector_type(4))) float f32x4;

#define LGKM0  asm volatile("s_waitcnt lgkmcnt(0)" ::: "memory")
#define VMCNT8 asm volatile("s_waitcnt vmcnt(8)" ::: "memory")
#define VMCNT4 asm volatile("s_waitcnt vmcnt(4)" ::: "memory")
#define VMCNT0 asm volatile("s_waitcnt vmcnt(0)" ::: "memory")
#define SBAR   __builtin_amdgcn_s_barrier()
#define SCHED0 __builtin_amdgcn_sched_barrier(0)

__device__ __forceinline__ unsigned short f2bf(float f) {
  union { float f; unsigned u; } v; v.f = f;
  return (unsigned short)((v.u + 0x7fffu + ((v.u >> 16) & 1u)) >> 16);
}

__device__ __forceinline__ void gld16(const void* g, void* l) {
  __builtin_amdgcn_global_load_lds(
      (const __attribute__((address_space(1))) unsigned int*)g,
      (__attribute__((address_space(3))) unsigned int*)l, 16, 0, 0);
}

// ---------------- fused fp32 -> bf16 convert (5 tensors, dst contiguous) ----
__global__ __launch_bounds__(256) void k_cvt5(
    const float* __restrict__ s0, const float* __restrict__ s1,
    const float* __restrict__ s2, const float* __restrict__ s3,
    const float* __restrict__ s4, unsigned short* __restrict__ dst) {
  int i = blockIdx.x * 256 + threadIdx.x;          // 5 * 2^22 chunks of 4 floats
  int tsel = i >> 22, il = i & 4194303;
  const float* s = tsel == 0 ? s0 : tsel == 1 ? s1 : tsel == 2 ? s2 : tsel == 3 ? s3 : s4;
  float4 v = reinterpret_cast<const float4*>(s)[il];
  ushort4 o;
  o.x = f2bf(v.x); o.y = f2bf(v.y); o.z = f2bf(v.z); o.w = f2bf(v.w);
  *reinterpret_cast<ushort4*>(dst + (size_t)i * 4) = o;
}

// ---------------- GEMM 256x256, BK=64, 8 waves, 8-phase (m201-faithful) ----
// Per phase: one 128x128 C-quadrant (qa,qb), 16 MFMA/wave; stage ONE
// half-tile (2 gld16/thread). vmcnt(4) ONLY at phases 4 and 8 (once per
// K-tile); lgkmcnt(0) AFTER the leading barrier. LDS 128 KiB dbuf.
// MODE 0: fp32 out [M,N]; MODE 1: RoPE+transpose -> bf16 [B,H,S,HD];
// MODE 2: V^T -> bf16 [B,H,HD,S] via LDS-bounce transpose.
template<int MODE>
__global__ __launch_bounds__(512, 1) void k_gemm(
    const unsigned short* __restrict__ A, const unsigned short* __restrict__ W,
    void* __restrict__ out, const float* __restrict__ sinp, const float* __restrict__ cosp)
{
  extern __shared__ unsigned short lds[];   // 131072 B
  const int K = TD;
  const int t = threadIdx.x;
  const int w = t >> 6, l = t & 63, lr = l & 15, lh = l >> 4;
  const int wm = w >> 2, wn = w & 3;        // 2 x 4 waves within quadrant

  // XCD swizzle (256 blocks = 8 XCD x 32, bijective)
  const int id = blockIdx.x;
  const int swz = (id & 7) * 32 + (id >> 3);
  const int m0 = (swz >> 4) * 256, n0 = (swz & 15) * 256;

  // per-lane LDS read offset within [16][32] subtile: chunk = lh ^ ((row>>1)&3)
  const int llo = lr * 32 + ((lh ^ ((lr >> 1) & 3)) * 8);

  const unsigned short* srcA = A + (size_t)m0 * K;
  const unsigned short* srcB = W + (size_t)n0 * K;

  // staging source offsets (k-invariant part); chunk c = it*512 + t
  int roff[2];
#pragma unroll
  for (int it = 0; it < 2; ++it) {
    int c = it * 512 + t;
    int rl = (c >> 2) & 15;
    roff[it] = (16 * (c >> 7) + rl) * K + ((c >> 6) & 1) * 32 + ((c & 3) ^ ((rl >> 1) & 3)) * 8;
  }

  f32x4 acc[2][2][4][2];    // [qa][qb][m][n]
#pragma unroll
  for (int qa = 0; qa < 2; ++qa)
#pragma unroll
    for (int qb = 0; qb < 2; ++qb)
#pragma unroll
      for (int m = 0; m < 4; ++m)
#pragma unroll
        for (int n = 0; n < 2; ++n) acc[qa][qb][m][n] = 0.f;

  bf16x8 af[4][2], bfv[2][2];

#define STG(SBUF, SAB, SHALF, SKOFS) { \
    const unsigned short* _s = (SAB) ? srcB : srcA; \
    const int _b = (SBUF)*32768 + (SAB)*16384 + (SHALF)*8192; \
    gld16(_s + (size_t)(SHALF)*128*TD + (SKOFS) + roff[0], &lds[_b + t*8]); \
    gld16(_s + (size_t)(SHALF)*128*TD + (SKOFS) + roff[1], &lds[_b + (512+t)*8]); }

  // phase: ds_reads -> stage issue -> [vmcnt(4) if K-tile boundary] ->
  //        barrier -> lgkm0 -> MFMA -> barrier
#define PHASE(BUF, QA, QB, DOAF, SBUF, SAB, SHALF, SKOFS, DOVM) { \
    if (DOAF) { \
      _Pragma("unroll") for (int m = 0; m < 4; ++m) \
      _Pragma("unroll") for (int kk = 0; kk < 2; ++kk) \
        af[m][kk] = *(const bf16x8*)&lds[(BUF)*32768 + (QA)*8192 + ((wm*4+m)*2+kk)*512 + llo]; \
    } \
    _Pragma("unroll") for (int n = 0; n < 2; ++n) \
    _Pragma("unroll") for (int kk = 0; kk < 2; ++kk) \
      bfv[n][kk] = *(const bf16x8*)&lds[(BUF)*32768 + 16384 + (QB)*8192 + ((wn*2+n)*2+kk)*512 + llo]; \
    STG(SBUF, SAB, SHALF, SKOFS); \
    if (DOVM) { VMCNT4; } \
    SBAR; \
    LGKM0; SCHED0; \
    __builtin_amdgcn_s_setprio(1); \
    _Pragma("unroll") for (int m = 0; m < 4; ++m) \
    _Pragma("unroll") for (int n = 0; n < 2; ++n) \
    _Pragma("unroll") for (int kk = 0; kk < 2; ++kk) \
      acc[QA][QB][m][n] = __builtin_amdgcn_mfma_f32_16x16x32_bf16(af[m][kk], bfv[n][kk], acc[QA][QB][m][n], 0,0,0); \
    __builtin_amdgcn_s_setprio(0); \
    SBAR; SCHED0; }

  const int NT = K / 64;      // 64 K-tiles

  // prologue: b0 fully (tau=0), b1 A.h0/B.h0 (tau=1); b1 h1 staged by P1/P2
  STG(0,0,0, 0);  SCHED0;
  STG(0,1,0, 0);  SCHED0;
  STG(0,0,1, 0);  SCHED0;
  STG(0,1,1, 0);  SCHED0;
  STG(1,0,0, 64); SCHED0;
  STG(1,1,0, 64); SCHED0;
  VMCNT4; SBAR; SCHED0;       // buf0 resident; b1.h0 (4 loads) still in flight

  for (int i2 = 0; i2 < NT/2; ++i2) {
    const int k1c = (2*i2+1) * 64;
    const int k0n = (2*i2+2 < NT ? 2*i2+2 : NT-1) * 64;
    const int k1n = (2*i2+3 < NT ? 2*i2+3 : NT-1) * 64;
    PHASE(0, 0,0, 1,  1,0,1, k1c, 0);   // stage b1.A.h1 (tau1)
    PHASE(0, 0,1, 0,  1,1,1, k1c, 0);   // stage b1.B.h1 (tau1)
    PHASE(0, 1,0, 1,  0,0,0, k0n, 0);   // stage b0.A.h0 (tau0+2)
    PHASE(0, 1,1, 0,  0,1,0, k0n, 1);   // stage b0.B.h0 ; vmcnt(4) -> buf1 ready
    PHASE(1, 0,0, 1,  0,0,1, k0n, 0);   // stage b0.A.h1
    PHASE(1, 0,1, 0,  0,1,1, k0n, 0);   // stage b0.B.h1
    PHASE(1, 1,0, 1,  1,0,0, k1n, 0);   // stage b1.A.h0 (tau1+2)
    PHASE(1, 1,1, 0,  1,1,0, k1n, 1);   // stage b1.B.h0 ; vmcnt(4) -> buf0 ready
  }
#undef PHASE
#undef STG

  // -------- epilogues --------
  if constexpr (MODE == 2) {
    // V^T [B,H,HD,S]: 8 passes over (qb,n); slab [64 cols][256 rows] in LDS.
    VMCNT0; SBAR;
    const int b = m0 >> 11, sbase = m0 & (TS - 1);
#pragma unroll
    for (int qb = 0; qb < 2; ++qb)
#pragma unroll
      for (int n = 0; n < 2; ++n) {
        __syncthreads();
#pragma unroll
        for (int qa = 0; qa < 2; ++qa)
#pragma unroll
          for (int m = 0; m < 4; ++m) {
            int lcol = wn * 16 + lr;
            int srow = qa * 128 + wm * 64 + m * 16 + lh * 4;
            ushort4 o;
            o.x = f2bf(acc[qa][qb][m][n][0]); o.y = f2bf(acc[qa][qb][m][n][1]);
            o.z = f2bf(acc[qa][qb][m][n][2]); o.w = f2bf(acc[qa][qb][m][n][3]);
            *(ushort4*)&lds[lcol * 268 + srow] = o;
          }
        __syncthreads();
#pragma unroll
        for (int rr = 0; rr < 4; ++rr) {
          int idx = rr * 512 + t;              // 2048 chunks: 64 cols x 32 x 16B
          int dl = idx >> 5, sc = (idx & 31) * 8;
          uint4 v = *(const uint4*)&lds[dl * 268 + sc];
          int d = n0 + qb * 128 + (dl >> 4) * 32 + n * 16 + (dl & 15);
          *(uint4*)((unsigned short*)out +
                    ((size_t)((b * TH + (d >> 8)) * THD + (d & 255))) * TS + sbase + sc) = v;
        }
      }
  } else {
#pragma unroll
    for (int qa = 0; qa < 2; ++qa)
#pragma unroll
      for (int qb = 0; qb < 2; ++qb)
#pragma unroll
        for (int m = 0; m < 4; ++m)
#pragma unroll
          for (int n = 0; n < 2; ++n)
#pragma unroll
            for (int r = 0; r < 4; ++r) {
              int row = m0 + qa * 128 + wm * 64 + m * 16 + lh * 4 + r;
              int col = n0 + qb * 128 + wn * 32 + n * 16 + lr;
              float x = acc[qa][qb][m][n][r];
              if constexpr (MODE == 0) {
                ((float*)out)[(size_t)row * TD + col] = x;
              } else {
                float part = __shfl_xor(x, 1, 64);
                int s = row & (TS - 1), b = row >> 11;
                int h = col >> 8, d = col & 255;
                float val = x;
                if (d < TROT) {
                  float cc = cosp[s * TROT + d], ss = sinp[s * TROT + d];
                  val = x * cc + ((d & 1) ? part : -part) * ss;
                }
                ((unsigned short*)out)[((size_t)(b * TH + h) * TS + s) * THD + d] = f2bf(val);
              }
            }
  }
}

// ---------------- causal flash attention, KVBLK=64 (unchanged) -------------
__global__ __launch_bounds__(256, 2) void k_fattn(
    const unsigned short* __restrict__ Qt, const unsigned short* __restrict__ Kt,
    const unsigned short* __restrict__ Vt, unsigned short* __restrict__ O)
{
  extern __shared__ unsigned short sh[];   // K 32KB | V 32KB | Ps 9KB
  const int t = threadIdx.x, w = t >> 6, l = t & 63, lr = l & 15, lh = l >> 4;
  const int bh = blockIdx.x;
  const int qb = (gridDim.y - 1) - blockIdx.y;   // LPT: heaviest first
  const int q0 = qb * 64;
  const int jmax = qb;

  const unsigned short* kbase = Kt + (size_t)bh * TS * THD;
  const unsigned short* vbase = Vt + (size_t)bh * THD * TS;

  const int llo = lr * 32 + ((lh ^ ((lr >> 1) & 3)) * 8);

  int koff[8], voff[8];
#pragma unroll
  for (int it = 0; it < 8; ++it) {
    int c = it * 256 + t;
    int row = (c >> 2) & 15;
    int scc = (c & 3) ^ ((row >> 1) & 3);
    koff[it] = (((c >> 9) & 3) * 16 + row) * THD + ((c >> 6) & 7) * 32 + scc * 8;
    voff[it] = (((c >> 6) & 15) * 16 + row) * TS + ((c >> 10) & 1) * 32 + scc * 8;
  }

  bf16x8 qf[8];
  const unsigned short* qp = Qt + ((size_t)bh * TS + q0 + w * 16 + lr) * THD;
#pragma unroll
  for (int kk = 0; kk < 8; ++kk) qf[kk] = *(const bf16x8*)(qp + kk * 32 + lh * 8);

  f32x4 oacc[16];
#pragma unroll
  for (int i = 0; i < 16; ++i) oacc[i] = 0.f;
  float mrow[4] = {-__builtin_inff(), -__builtin_inff(), -__builtin_inff(), -__builtin_inff()};
  float lrow[4] = {0.f, 0.f, 0.f, 0.f};

#pragma unroll
  for (int it = 0; it < 8; ++it) gld16(kbase + koff[it], &sh[(it*256 + t) * 8]);
#pragma unroll
  for (int it = 0; it < 8; ++it) gld16(vbase + voff[it], &sh[16384 + (it*256 + t) * 8]);

  for (int j = 0; j <= jmax; ++j) {
    const bool nx = (j < jmax);
    VMCNT8; SBAR; SCHED0;

    f32x4 sacc[4];
#pragma unroll
    for (int nt = 0; nt < 4; ++nt) sacc[nt] = 0.f;
    __builtin_amdgcn_s_setprio(1);
#pragma unroll
    for (int nt = 0; nt < 4; ++nt)
#pragma unroll
      for (int kk = 0; kk < 8; ++kk) {
        bf16x8 kf = *(const bf16x8*)&sh[(nt*8 + kk)*512 + llo];
        sacc[nt] = __builtin_amdgcn_mfma_f32_16x16x32_bf16(qf[kk], kf, sacc[nt], 0, 0, 0);
      }
    __builtin_amdgcn_s_setprio(0);
    LGKM0; SBAR; SCHED0;
    if (nx) {
      const unsigned short* kj = kbase + (size_t)(j + 1) * 64 * THD;
#pragma unroll
      for (int it = 0; it < 8; ++it) gld16(kj + koff[it], &sh[(it*256 + t) * 8]);
    }

    float p[4][4], tmax[4];
    const int qrow0 = q0 + w * 16 + lh * 4;
#pragma unroll
    for (int r = 0; r < 4; ++r) tmax[r] = -__builtin_inff();
#pragma unroll
    for (int nt = 0; nt < 4; ++nt) {
      int kpos = j * 64 + nt * 16 + lr;
#pragma unroll
      for (int r = 0; r < 4; ++r) {
        float sv = sacc[nt][r] * 0.0625f;
        if (kpos > qrow0 + r) sv = -__builtin_inff();
        p[nt][r] = sv;
        tmax[r] = fmaxf(tmax[r], sv);
      }
    }
#pragma unroll
    for (int off = 1; off < 16; off <<= 1)
#pragma unroll
      for (int r = 0; r < 4; ++r) tmax[r] = fmaxf(tmax[r], __shfl_xor(tmax[r], off, 64));

    float g = fmaxf(fmaxf(tmax[0] - mrow[0], tmax[1] - mrow[1]),
                    fmaxf(tmax[2] - mrow[2], tmax[3] - mrow[3]));
    if (__any(g > 8.f)) {
      float alpha[4];
#pragma unroll
      for (int r = 0; r < 4; ++r) {
        float mn = fmaxf(mrow[r], tmax[r]);
        alpha[r] = __expf(mrow[r] - mn);
        mrow[r] = mn;
        lrow[r] *= alpha[r];
      }
#pragma unroll
      for (int i = 0; i < 16; ++i)
#pragma unroll
        for (int r = 0; r < 4; ++r) oacc[i][r] *= alpha[r];
    }

    float tsum[4] = {0.f, 0.f, 0.f, 0.f};
#pragma unroll
    for (int nt = 0; nt < 4; ++nt)
#pragma unroll
      for (int r = 0; r < 4; ++r) {
        float pe = __expf(p[nt][r] - mrow[r]);
        p[nt][r] = pe;
        tsum[r] += pe;
      }
#pragma unroll
    for (int off = 1; off < 16; off <<= 1)
#pragma unroll
      for (int r = 0; r < 4; ++r) tsum[r] += __shfl_xor(tsum[r], off, 64);
#pragma unroll
    for (int r = 0; r < 4; ++r) lrow[r] += tsum[r];

    const int wb = 32768 + w * 1152;
#pragma unroll
    for (int nt = 0; nt < 4; ++nt)
#pragma unroll
      for (int r = 0; r < 4; ++r)
        sh[wb + (lh*4 + r)*72 + nt*16 + lr] = f2bf(p[nt][r]);
    bf16x8 pfr0 = *(const bf16x8*)&sh[wb + lr*72 + lh*8];
    bf16x8 pfr1 = *(const bf16x8*)&sh[wb + lr*72 + 32 + lh*8];

    if (nx) { VMCNT8; } else { VMCNT0; }
    SBAR; SCHED0;
    __builtin_amdgcn_s_setprio(1);
#pragma unroll
    for (int dt = 0; dt < 16; ++dt) {
      bf16x8 vf = *(const bf16x8*)&sh[16384 + dt*512 + llo];
      oacc[dt] = __builtin_amdgcn_mfma_f32_16x16x32_bf16(pfr0, vf, oacc[dt], 0, 0, 0);
    }
#pragma unroll
    for (int dt = 0; dt < 16; ++dt) {
      bf16x8 vf = *(const bf16x8*)&sh[16384 + (16 + dt)*512 + llo];
      oacc[dt] = __builtin_amdgcn_mfma_f32_16x16x32_bf16(pfr1, vf, oacc[dt], 0, 0, 0);
    }
    __builtin_amdgcn_s_setprio(0);
    LGKM0; SBAR; SCHED0;
    if (nx) {
      const unsigned short* vj = vbase + (size_t)(j + 1) * 64;
#pragma unroll
      for (int it = 0; it < 8; ++it) gld16(vj + voff[it], &sh[16384 + (it*256 + t) * 8]);
    }
  }

  const int b = bh >> 4, h = bh & 15;
  float inv[4];
#pragma unroll
  for (int r = 0; r < 4; ++r) inv[r] = 1.f / lrow[r];
#pragma unroll
  for (int dt = 0; dt < 16; ++dt)
#pragma unroll
    for (int r = 0; r < 4; ++r) {
      int s = q0 + w * 16 + lh * 4 + r;
      O[((size_t)(b * TS + s) * TH + h) * THD + dt * 16 + lr] = f2bf(oacc[dt][r] * inv[r]);
    }
}

// ---------------- launch ----------------
extern "C" void kernel_launch(void* const* d_in, const int* in_sizes, int n_in,
                              void* d_out, int out_size, void* d_ws, size_t ws_size,
                              hipStream_t stream) {
  const float* hs   = (const float*)d_in[0];
  const float* sinp = (const float*)d_in[1];
  const float* cosp = (const float*)d_in[2];
  const float* Wq   = (const float*)d_in[3];
  const float* Wk   = (const float*)d_in[4];
  const float* Wv   = (const float*)d_in[5];
  const float* Wo   = (const float*)d_in[6];

  const size_t NE = (size_t)TM * TD;
  const size_t BYTES = NE * 2;
  char* ws = (char*)d_ws;
  unsigned short* hsb = (unsigned short*)(ws + 0*BYTES);
  unsigned short* Wqb = (unsigned short*)(ws + 1*BYTES);
  unsigned short* Wkb = (unsigned short*)(ws + 2*BYTES);
  unsigned short* Wvb = (unsigned short*)(ws + 3*BYTES);
  unsigned short* Wob = (unsigned short*)(ws + 4*BYTES);
  unsigned short* Qt  = (unsigned short*)(ws + 5*BYTES);  // [B,H,S,HD]
  unsigned short* Ktb = (unsigned short*)(ws + 6*BYTES);  // [B,H,S,HD]
  unsigned short* Vtb = (unsigned short*)(ws + 7*BYTES);  // [B,H,HD,S]
  unsigned short* Ob  = (unsigned short*)(ws + 8*BYTES);  // [B,S,H,HD] == [M,D]

  k_cvt5<<<81920, 256, 0, stream>>>(hs, Wq, Wk, Wv, Wo, hsb);

  k_gemm<1><<<256, 512, 131072, stream>>>(hsb, Wqb, (void*)Qt,  sinp, cosp);
  k_gemm<1><<<256, 512, 131072, stream>>>(hsb, Wkb, (void*)Ktb, sinp, cosp);
  k_gemm<2><<<256, 512, 131072, stream>>>(hsb, Wvb, (void*)Vtb, nullptr, nullptr);

  k_fattn<<<dim3(TB*TH, TS/64), 256, 74752, stream>>>(Qt, Ktb, Vtb, Ob);

  k_gemm<0><<<256, 512, 131072, stream>>>(Ob, Wob, d_out, nullptr, nullptr);
}

// Round 8
// 725.020 us; speedup vs baseline: 1.9136x; 1.0182x over previous
//
#include <hip/hip_runtime.h>
#include <cstdint>
#include <cstddef>

#define TB 2
#define TS 2048
#define TD 4096
#define TH 16
#define THD 256
#define TROT 64
#define TM (TB*TS)

typedef __attribute__((ext_vector_type(8))) short bf16x8;
typedef __attribute__((ext_vector_type(4))) float f32x4;

#define LGKM0  asm volatile("s_waitcnt lgkmcnt(0)" ::: "memory")
#define VMCNT8 asm volatile("s_waitcnt vmcnt(8)" ::: "memory")
#define VMCNT4 asm volatile("s_waitcnt vmcnt(4)" ::: "memory")
#define VMCNT0 asm volatile("s_waitcnt vmcnt(0)" ::: "memory")
#define SBAR   __builtin_amdgcn_s_barrier()
#define SCHED0 __builtin_amdgcn_sched_barrier(0)

__device__ __forceinline__ unsigned short f2bf(float f) {
  union { float f; unsigned u; } v; v.f = f;
  return (unsigned short)((v.u + 0x7fffu + ((v.u >> 16) & 1u)) >> 16);
}

__device__ __forceinline__ void gld16(const void* g, void* l) {
  __builtin_amdgcn_global_load_lds(
      (const __attribute__((address_space(1))) unsigned int*)g,
      (__attribute__((address_space(3))) unsigned int*)l, 16, 0, 0);
}

// ---------------- fused fp32 -> bf16 convert (5 tensors, dst contiguous) ----
__global__ __launch_bounds__(256) void k_cvt5(
    const float* __restrict__ s0, const float* __restrict__ s1,
    const float* __restrict__ s2, const float* __restrict__ s3,
    const float* __restrict__ s4, unsigned short* __restrict__ dst) {
  int i = blockIdx.x * 256 + threadIdx.x;          // 5 * 2^22 chunks of 4 floats
  int tsel = i >> 22, il = i & 4194303;
  const float* s = tsel == 0 ? s0 : tsel == 1 ? s1 : tsel == 2 ? s2 : tsel == 3 ? s3 : s4;
  float4 v = reinterpret_cast<const float4*>(s)[il];
  ushort4 o;
  o.x = f2bf(v.x); o.y = f2bf(v.y); o.z = f2bf(v.z); o.w = f2bf(v.w);
  *reinterpret_cast<ushort4*>(dst + (size_t)i * 4) = o;
}

// ---------------- GEMM 256x256, BK=64, 8 waves, 8-phase ----------------
// B quadrant fragments (bq0/bq1) cached in registers for the whole buf
// (24 ds_read_b128 per K-tile/wave instead of 32); A re-read per qa-phase.
// vmcnt(4) only at phases 4/8; lgkm only in phases that issue ds_reads.
// MODE 0: fp32 out [M,N]; MODE 1: RoPE+transpose -> bf16 [B,H,S,HD];
// MODE 2: V^T -> bf16 [B,H,HD,S] via LDS-bounce transpose.
template<int MODE>
__global__ __launch_bounds__(512, 1) void k_gemm(
    const unsigned short* __restrict__ A, const unsigned short* __restrict__ W,
    void* __restrict__ out, const float* __restrict__ sinp, const float* __restrict__ cosp)
{
  extern __shared__ unsigned short lds[];   // 131072 B
  const int K = TD;
  const int t = threadIdx.x;
  const int w = t >> 6, l = t & 63, lr = l & 15, lh = l >> 4;
  const int wm = w >> 2, wn = w & 3;        // 2 x 4 waves within quadrant

  // XCD swizzle (256 blocks = 8 XCD x 32, bijective)
  const int id = blockIdx.x;
  const int swz = (id & 7) * 32 + (id >> 3);
  const int m0 = (swz >> 4) * 256, n0 = (swz & 15) * 256;

  // per-lane LDS read offset within [16][32] subtile: chunk = lh ^ ((row>>1)&3)
  const int llo = lr * 32 + ((lh ^ ((lr >> 1) & 3)) * 8);

  const unsigned short* srcA = A + (size_t)m0 * K;
  const unsigned short* srcB = W + (size_t)n0 * K;

  // staging source offsets (k-invariant part); chunk c = it*512 + t
  int roff[2];
#pragma unroll
  for (int it = 0; it < 2; ++it) {
    int c = it * 512 + t;
    int rl = (c >> 2) & 15;
    roff[it] = (16 * (c >> 7) + rl) * K + ((c >> 6) & 1) * 32 + ((c & 3) ^ ((rl >> 1) & 3)) * 8;
  }

  f32x4 acc[2][2][4][2];    // [qa][qb][m][n]
#pragma unroll
  for (int qa = 0; qa < 2; ++qa)
#pragma unroll
    for (int qb = 0; qb < 2; ++qb)
#pragma unroll
      for (int m = 0; m < 4; ++m)
#pragma unroll
        for (int n = 0; n < 2; ++n) acc[qa][qb][m][n] = 0.f;

  bf16x8 af[4][2], bq0[2][2], bq1[2][2];

#define STG(SBUF, SAB, SHALF, SKOFS) { \
    const unsigned short* _s = (SAB) ? srcB : srcA; \
    const int _b = (SBUF)*32768 + (SAB)*16384 + (SHALF)*8192; \
    gld16(_s + (size_t)(SHALF)*128*TD + (SKOFS) + roff[0], &lds[_b + t*8]); \
    gld16(_s + (size_t)(SHALF)*128*TD + (SKOFS) + roff[1], &lds[_b + (512+t)*8]); }

  // phase: [ds_reads] -> stage issue -> [vmcnt(4)] -> barrier ->
  //        [lgkm0 if reads] -> MFMA (kk-outer, independent x8) -> barrier
#define PH(BUF, QA, QB, LDAF, LDB0, LDB1, SBUF, SAB, SHALF, SKOFS, DOVM) { \
    if (LDAF) { \
      _Pragma("unroll") for (int m = 0; m < 4; ++m) \
      _Pragma("unroll") for (int kk = 0; kk < 2; ++kk) \
        af[m][kk] = *(const bf16x8*)&lds[(BUF)*32768 + (QA)*8192 + ((wm*4+m)*2+kk)*512 + llo]; \
    } \
    if (LDB0) { \
      _Pragma("unroll") for (int n = 0; n < 2; ++n) \
      _Pragma("unroll") for (int kk = 0; kk < 2; ++kk) \
        bq0[n][kk] = *(const bf16x8*)&lds[(BUF)*32768 + 16384 + ((wn*2+n)*2+kk)*512 + llo]; \
    } \
    if (LDB1) { \
      _Pragma("unroll") for (int n = 0; n < 2; ++n) \
      _Pragma("unroll") for (int kk = 0; kk < 2; ++kk) \
        bq1[n][kk] = *(const bf16x8*)&lds[(BUF)*32768 + 16384 + 8192 + ((wn*2+n)*2+kk)*512 + llo]; \
    } \
    STG(SBUF, SAB, SHALF, SKOFS); \
    if (DOVM) { VMCNT4; } \
    SBAR; \
    if ((LDAF) || (LDB0) || (LDB1)) { LGKM0; } \
    SCHED0; \
    __builtin_amdgcn_s_setprio(1); \
    _Pragma("unroll") for (int kk = 0; kk < 2; ++kk) \
    _Pragma("unroll") for (int m = 0; m < 4; ++m) \
    _Pragma("unroll") for (int n = 0; n < 2; ++n) \
      acc[QA][QB][m][n] = __builtin_amdgcn_mfma_f32_16x16x32_bf16( \
          af[m][kk], (QB) ? bq1[n][kk] : bq0[n][kk], acc[QA][QB][m][n], 0,0,0); \
    __builtin_amdgcn_s_setprio(0); \
    SBAR; SCHED0; }

  const int NT = K / 64;      // 64 K-tiles

  // prologue: b0 fully (tau=0), b1 A.h0/B.h0 (tau=1); b1 h1 staged by P1/P2
  STG(0,0,0, 0);  SCHED0;
  STG(0,1,0, 0);  SCHED0;
  STG(0,0,1, 0);  SCHED0;
  STG(0,1,1, 0);  SCHED0;
  STG(1,0,0, 64); SCHED0;
  STG(1,1,0, 64); SCHED0;
  VMCNT4; SBAR; SCHED0;       // buf0 resident; b1.h0 (4 loads) still in flight

  for (int i2 = 0; i2 < NT/2; ++i2) {
    const int k1c = (2*i2+1) * 64;
    const int k0n = (2*i2+2 < NT ? 2*i2+2 : NT-1) * 64;
    const int k1n = (2*i2+3 < NT ? 2*i2+3 : NT-1) * 64;
    PH(0, 0,0, 1,1,0,  1,0,1, k1c, 0);   // af(b0,qa0)+bq0 ; stage b1.A.h1
    PH(0, 0,1, 0,0,1,  1,1,1, k1c, 0);   // bq1            ; stage b1.B.h1
    PH(0, 1,0, 1,0,0,  0,0,0, k0n, 0);   // af(b0,qa1)     ; stage b0.A.h0'
    PH(0, 1,1, 0,0,0,  0,1,0, k0n, 1);   //                ; stage b0.B.h0' ; vmcnt(4)
    PH(1, 0,0, 1,1,0,  0,0,1, k0n, 0);   // af(b1,qa0)+bq0 ; stage b0.A.h1'
    PH(1, 0,1, 0,0,1,  0,1,1, k0n, 0);   // bq1            ; stage b0.B.h1'
    PH(1, 1,0, 1,0,0,  1,0,0, k1n, 0);   // af(b1,qa1)     ; stage b1.A.h0''
    PH(1, 1,1, 0,0,0,  1,1,0, k1n, 1);   //                ; stage b1.B.h0'' ; vmcnt(4)
  }
#undef PH
#undef STG

  VMCNT0;   // drain pending gld16 before LDS reuse / kernel end

  // -------- epilogues --------
  if constexpr (MODE == 2) {
    // V^T [B,H,HD,S]: 8 passes over (qb,n); slab [64 cols][256 rows] in LDS.
    SBAR;
    const int b = m0 >> 11, sbase = m0 & (TS - 1);
#pragma unroll
    for (int qb = 0; qb < 2; ++qb)
#pragma unroll
      for (int n = 0; n < 2; ++n) {
        __syncthreads();
#pragma unroll
        for (int qa = 0; qa < 2; ++qa)
#pragma unroll
          for (int m = 0; m < 4; ++m) {
            int lcol = wn * 16 + lr;
            int srow = qa * 128 + wm * 64 + m * 16 + lh * 4;
            ushort4 o;
            o.x = f2bf(acc[qa][qb][m][n][0]); o.y = f2bf(acc[qa][qb][m][n][1]);
            o.z = f2bf(acc[qa][qb][m][n][2]); o.w = f2bf(acc[qa][qb][m][n][3]);
            *(ushort4*)&lds[lcol * 268 + srow] = o;
          }
        __syncthreads();
#pragma unroll
        for (int rr = 0; rr < 4; ++rr) {
          int idx = rr * 512 + t;              // 2048 chunks: 64 cols x 32 x 16B
          int dl = idx >> 5, sc = (idx & 31) * 8;
          uint4 v = *(const uint4*)&lds[dl * 268 + sc];
          int d = n0 + qb * 128 + (dl >> 4) * 32 + n * 16 + (dl & 15);
          *(uint4*)((unsigned short*)out +
                    ((size_t)((b * TH + (d >> 8)) * THD + (d & 255))) * TS + sbase + sc) = v;
        }
      }
  } else {
#pragma unroll
    for (int qa = 0; qa < 2; ++qa)
#pragma unroll
      for (int qb = 0; qb < 2; ++qb)
#pragma unroll
        for (int m = 0; m < 4; ++m)
#pragma unroll
          for (int n = 0; n < 2; ++n)
#pragma unroll
            for (int r = 0; r < 4; ++r) {
              int row = m0 + qa * 128 + wm * 64 + m * 16 + lh * 4 + r;
              int col = n0 + qb * 128 + wn * 32 + n * 16 + lr;
              float x = acc[qa][qb][m][n][r];
              if constexpr (MODE == 0) {
                ((float*)out)[(size_t)row * TD + col] = x;
              } else {
                float part = __shfl_xor(x, 1, 64);
                int s = row & (TS - 1), b = row >> 11;
                int h = col >> 8, d = col & 255;
                float val = x;
                if (d < TROT) {
                  float cc = cosp[s * TROT + d], ss = sinp[s * TROT + d];
                  val = x * cc + ((d & 1) ? part : -part) * ss;
                }
                ((unsigned short*)out)[((size_t)(b * TH + h) * TS + s) * THD + d] = f2bf(val);
              }
            }
  }
}

// ---------------- causal flash attention, KVBLK=64 -------------------------
__global__ __launch_bounds__(256, 2) void k_fattn(
    const unsigned short* __restrict__ Qt, const unsigned short* __restrict__ Kt,
    const unsigned short* __restrict__ Vt, unsigned short* __restrict__ O)
{
  extern __shared__ unsigned short sh[];   // K 32KB | V 32KB | Ps 9KB
  const int t = threadIdx.x, w = t >> 6, l = t & 63, lr = l & 15, lh = l >> 4;
  const int bh = blockIdx.x;
  const int qb = (gridDim.y - 1) - blockIdx.y;   // LPT: heaviest first
  const int q0 = qb * 64;
  const int jmax = qb;

  const unsigned short* kbase = Kt + (size_t)bh * TS * THD;
  const unsigned short* vbase = Vt + (size_t)bh * THD * TS;

  const int llo = lr * 32 + ((lh ^ ((lr >> 1) & 3)) * 8);

  int koff[8], voff[8];
#pragma unroll
  for (int it = 0; it < 8; ++it) {
    int c = it * 256 + t;
    int row = (c >> 2) & 15;
    int scc = (c & 3) ^ ((row >> 1) & 3);
    koff[it] = (((c >> 9) & 3) * 16 + row) * THD + ((c >> 6) & 7) * 32 + scc * 8;
    voff[it] = (((c >> 6) & 15) * 16 + row) * TS + ((c >> 10) & 1) * 32 + scc * 8;
  }

  bf16x8 qf[8];
  const unsigned short* qp = Qt + ((size_t)bh * TS + q0 + w * 16 + lr) * THD;
#pragma unroll
  for (int kk = 0; kk < 8; ++kk) qf[kk] = *(const bf16x8*)(qp + kk * 32 + lh * 8);

  f32x4 oacc[16];
#pragma unroll
  for (int i = 0; i < 16; ++i) oacc[i] = 0.f;
  float mrow[4] = {-__builtin_inff(), -__builtin_inff(), -__builtin_inff(), -__builtin_inff()};
  float lrow[4] = {0.f, 0.f, 0.f, 0.f};

#pragma unroll
  for (int it = 0; it < 8; ++it) gld16(kbase + koff[it], &sh[(it*256 + t) * 8]);
#pragma unroll
  for (int it = 0; it < 8; ++it) gld16(vbase + voff[it], &sh[16384 + (it*256 + t) * 8]);

  for (int j = 0; j <= jmax; ++j) {
    const bool nx = (j < jmax);
    VMCNT8; SBAR; SCHED0;

    f32x4 sacc[4];
#pragma unroll
    for (int nt = 0; nt < 4; ++nt) sacc[nt] = 0.f;
    __builtin_amdgcn_s_setprio(1);
#pragma unroll
    for (int kk = 0; kk < 8; ++kk)          // kk-outer: 4 independent MFMAs
#pragma unroll
      for (int nt = 0; nt < 4; ++nt) {
        bf16x8 kf = *(const bf16x8*)&sh[(nt*8 + kk)*512 + llo];
        sacc[nt] = __builtin_amdgcn_mfma_f32_16x16x32_bf16(qf[kk], kf, sacc[nt], 0, 0, 0);
      }
    __builtin_amdgcn_s_setprio(0);
    LGKM0; SBAR; SCHED0;
    if (nx) {
      const unsigned short* kj = kbase + (size_t)(j + 1) * 64 * THD;
#pragma unroll
      for (int it = 0; it < 8; ++it) gld16(kj + koff[it], &sh[(it*256 + t) * 8]);
    }

    float p[4][4], tmax[4];
    const int qrow0 = q0 + w * 16 + lh * 4;
#pragma unroll
    for (int r = 0; r < 4; ++r) tmax[r] = -__builtin_inff();
#pragma unroll
    for (int nt = 0; nt < 4; ++nt) {
      int kpos = j * 64 + nt * 16 + lr;
#pragma unroll
      for (int r = 0; r < 4; ++r) {
        float sv = sacc[nt][r] * 0.0625f;
        if (kpos > qrow0 + r) sv = -__builtin_inff();
        p[nt][r] = sv;
        tmax[r] = fmaxf(tmax[r], sv);
      }
    }
#pragma unroll
    for (int off = 1; off < 16; off <<= 1)
#pragma unroll
      for (int r = 0; r < 4; ++r) tmax[r] = fmaxf(tmax[r], __shfl_xor(tmax[r], off, 64));

    float g = fmaxf(fmaxf(tmax[0] - mrow[0], tmax[1] - mrow[1]),
                    fmaxf(tmax[2] - mrow[2], tmax[3] - mrow[3]));
    if (__any(g > 8.f)) {
      float alpha[4];
#pragma unroll
      for (int r = 0; r < 4; ++r) {
        float mn = fmaxf(mrow[r], tmax[r]);
        alpha[r] = __expf(mrow[r] - mn);
        mrow[r] = mn;
        lrow[r] *= alpha[r];
      }
#pragma unroll
      for (int i = 0; i < 16; ++i)
#pragma unroll
        for (int r = 0; r < 4; ++r) oacc[i][r] *= alpha[r];
    }

    float tsum[4] = {0.f, 0.f, 0.f, 0.f};
#pragma unroll
    for (int nt = 0; nt < 4; ++nt)
#pragma unroll
      for (int r = 0; r < 4; ++r) {
        float pe = __expf(p[nt][r] - mrow[r]);
        p[nt][r] = pe;
        tsum[r] += pe;
      }
#pragma unroll
    for (int off = 1; off < 16; off <<= 1)
#pragma unroll
      for (int r = 0; r < 4; ++r) tsum[r] += __shfl_xor(tsum[r], off, 64);
#pragma unroll
    for (int r = 0; r < 4; ++r) lrow[r] += tsum[r];

    const int wb = 32768 + w * 1152;
#pragma unroll
    for (int nt = 0; nt < 4; ++nt)
#pragma unroll
      for (int r = 0; r < 4; ++r)
        sh[wb + (lh*4 + r)*72 + nt*16 + lr] = f2bf(p[nt][r]);
    bf16x8 pfr0 = *(const bf16x8*)&sh[wb + lr*72 + lh*8];
    bf16x8 pfr1 = *(const bf16x8*)&sh[wb + lr*72 + 32 + lh*8];

    if (nx) { VMCNT8; } else { VMCNT0; }
    SBAR; SCHED0;
    __builtin_amdgcn_s_setprio(1);
#pragma unroll
    for (int dt = 0; dt < 16; ++dt) {
      bf16x8 vf = *(const bf16x8*)&sh[16384 + dt*512 + llo];
      oacc[dt] = __builtin_amdgcn_mfma_f32_16x16x32_bf16(pfr0, vf, oacc[dt], 0, 0, 0);
    }
#pragma unroll
    for (int dt = 0; dt < 16; ++dt) {
      bf16x8 vf = *(const bf16x8*)&sh[16384 + (16 + dt)*512 + llo];
      oacc[dt] = __builtin_amdgcn_mfma_f32_16x16x32_bf16(pfr1, vf, oacc[dt], 0, 0, 0);
    }
    __builtin_amdgcn_s_setprio(0);
    LGKM0; SBAR; SCHED0;
    if (nx) {
      const unsigned short* vj = vbase + (size_t)(j + 1) * 64;
#pragma unroll
      for (int it = 0; it < 8; ++it) gld16(vj + voff[it], &sh[16384 + (it*256 + t) * 8]);
    }
  }

  const int b = bh >> 4, h = bh & 15;
  float inv[4];
#pragma unroll
  for (int r = 0; r < 4; ++r) inv[r] = 1.f / lrow[r];
#pragma unroll
  for (int dt = 0; dt < 16; ++dt)
#pragma unroll
    for (int r = 0; r < 4; ++r) {
      int s = q0 + w * 16 + lh * 4 + r;
      O[((size_t)(b * TS + s) * TH + h) * THD + dt * 16 + lr] = f2bf(oacc[dt][r] * inv[r]);
    }
}

// ---------------- launch ----------------
extern "C" void kernel_launch(void* const* d_in, const int* in_sizes, int n_in,
                              void* d_out, int out_size, void* d_ws, size_t ws_size,
                              hipStream_t stream) {
  const float* hs   = (const float*)d_in[0];
  const float* sinp = (const float*)d_in[1];
  const float* cosp = (const float*)d_in[2];
  const float* Wq   = (const float*)d_in[3];
  const float* Wk   = (const float*)d_in[4];
  const float* Wv   = (const float*)d_in[5];
  const float* Wo   = (const float*)d_in[6];

  const size_t NE = (size_t)TM * TD;
  const size_t BYTES = NE * 2;
  char* ws = (char*)d_ws;
  unsigned short* hsb = (unsigned short*)(ws + 0*BYTES);
  unsigned short* Wqb = (unsigned short*)(ws + 1*BYTES);
  unsigned short* Wkb = (unsigned short*)(ws + 2*BYTES);
  unsigned short* Wvb = (unsigned short*)(ws + 3*BYTES);
  unsigned short* Wob = (unsigned short*)(ws + 4*BYTES);
  unsigned short* Qt  = (unsigned short*)(ws + 5*BYTES);  // [B,H,S,HD]
  unsigned short* Ktb = (unsigned short*)(ws + 6*BYTES);  // [B,H,S,HD]
  unsigned short* Vtb = (unsigned short*)(ws + 7*BYTES);  // [B,H,HD,S]
  unsigned short* Ob  = (unsigned short*)(ws + 8*BYTES);  // [B,S,H,HD] == [M,D]

  k_cvt5<<<81920, 256, 0, stream>>>(hs, Wq, Wk, Wv, Wo, hsb);

  k_gemm<1><<<256, 512, 131072, stream>>>(hsb, Wqb, (void*)Qt,  sinp, cosp);
  k_gemm<1><<<256, 512, 131072, stream>>>(hsb, Wkb, (void*)Ktb, sinp, cosp);
  k_gemm<2><<<256, 512, 131072, stream>>>(hsb, Wvb, (void*)Vtb, nullptr, nullptr);

  k_fattn<<<dim3(TB*TH, TS/64), 256, 74752, stream>>>(Qt, Ktb, Vtb, Ob);

  k_gemm<0><<<256, 512, 131072, stream>>>(Ob, Wob, d_out, nullptr, nullptr);
}

// Round 9
// 722.848 us; speedup vs baseline: 1.9194x; 1.0030x over previous
//
#include <hip/hip_runtime.h>
#include <cstdint>
#include <cstddef>

#define TB 2
#define TS 2048
#define TD 4096
#define TH 16
#define THD 256
#define TROT 64
#define TM (TB*TS)

typedef __attribute__((ext_vector_type(8))) short bf16x8;
typedef __attribute__((ext_vector_type(4))) float f32x4;

#define LGKM0  asm volatile("s_waitcnt lgkmcnt(0)" ::: "memory")
#define VMCNT8 asm volatile("s_waitcnt vmcnt(8)" ::: "memory")
#define VMCNT4 asm volatile("s_waitcnt vmcnt(4)" ::: "memory")
#define VMCNT0 asm volatile("s_waitcnt vmcnt(0)" ::: "memory")
#define SBAR   __builtin_amdgcn_s_barrier()
#define SCHED0 __builtin_amdgcn_sched_barrier(0)
#define PRIO1  __builtin_amdgcn_s_setprio(1)
#define PRIO0  __builtin_amdgcn_s_setprio(0)

__device__ __forceinline__ unsigned short f2bf(float f) {
  union { float f; unsigned u; } v; v.f = f;
  return (unsigned short)((v.u + 0x7fffu + ((v.u >> 16) & 1u)) >> 16);
}

__device__ __forceinline__ void gld16(const void* g, void* l) {
  __builtin_amdgcn_global_load_lds(
      (const __attribute__((address_space(1))) unsigned int*)g,
      (__attribute__((address_space(3))) unsigned int*)l, 16, 0, 0);
}

// ---------------- fused fp32 -> bf16 convert (5 tensors, dst contiguous) ----
__global__ __launch_bounds__(256) void k_cvt5(
    const float* __restrict__ s0, const float* __restrict__ s1,
    const float* __restrict__ s2, const float* __restrict__ s3,
    const float* __restrict__ s4, unsigned short* __restrict__ dst) {
  int i = blockIdx.x * 256 + threadIdx.x;          // 5 * 2^22 chunks of 4 floats
  int tsel = i >> 22, il = i & 4194303;
  const float* s = tsel == 0 ? s0 : tsel == 1 ? s1 : tsel == 2 ? s2 : tsel == 3 ? s3 : s4;
  float4 v = reinterpret_cast<const float4*>(s)[il];
  ushort4 o;
  o.x = f2bf(v.x); o.y = f2bf(v.y); o.z = f2bf(v.z); o.w = f2bf(v.w);
  *reinterpret_cast<ushort4*>(dst + (size_t)i * 4) = o;
}

// ---------------- GEMM 256x256, BK=64, 8 waves, 8-phase + frag prefetch ----
// Fragment regs double-buffered (afP/afQ, bqP/bqQ); each phase's ds_reads
// are issued inside the PREVIOUS phase's MFMA cluster so the LDS pipe
// overlaps the MFMA pipe. Cross-buffer loads only at P1/P5 (after the
// vmcnt(4)+barrier that publishes the buffer block-wide).
// MODE 0: fp32 out [M,N]; MODE 1: RoPE+transpose -> bf16 [B,H,S,HD];
// MODE 2: V^T -> bf16 [B,H,HD,S] via LDS-bounce transpose.
template<int MODE>
__global__ __launch_bounds__(512, 1) void k_gemm(
    const unsigned short* __restrict__ A, const unsigned short* __restrict__ W,
    void* __restrict__ out, const float* __restrict__ sinp, const float* __restrict__ cosp)
{
  extern __shared__ unsigned short lds[];   // 131072 B
  const int K = TD;
  const int t = threadIdx.x;
  const int w = t >> 6, l = t & 63, lr = l & 15, lh = l >> 4;
  const int wm = w >> 2, wn = w & 3;        // 2 x 4 waves within quadrant

  // XCD swizzle (256 blocks = 8 XCD x 32, bijective)
  const int id = blockIdx.x;
  const int swz = (id & 7) * 32 + (id >> 3);
  const int m0 = (swz >> 4) * 256, n0 = (swz & 15) * 256;

  // per-lane LDS read offset within [16][32] subtile: chunk = lh ^ ((row>>1)&3)
  const int llo = lr * 32 + ((lh ^ ((lr >> 1) & 3)) * 8);

  const unsigned short* srcA = A + (size_t)m0 * K;
  const unsigned short* srcB = W + (size_t)n0 * K;

  // staging source offsets (k-invariant part); chunk c = it*512 + t
  int roff[2];
#pragma unroll
  for (int it = 0; it < 2; ++it) {
    int c = it * 512 + t;
    int rl = (c >> 2) & 15;
    roff[it] = (16 * (c >> 7) + rl) * K + ((c >> 6) & 1) * 32 + ((c & 3) ^ ((rl >> 1) & 3)) * 8;
  }

  f32x4 acc[2][2][4][2];    // [qa][qb][m][n]
#pragma unroll
  for (int qa = 0; qa < 2; ++qa)
#pragma unroll
    for (int qb = 0; qb < 2; ++qb)
#pragma unroll
      for (int m = 0; m < 4; ++m)
#pragma unroll
        for (int n = 0; n < 2; ++n) acc[qa][qb][m][n] = 0.f;

  bf16x8 afP[4][2], afQ[4][2], bqP[2][2], bqQ[2][2];

#define STG(SBUF, SAB, SHALF, SKOFS) { \
    const unsigned short* _s = (SAB) ? srcB : srcA; \
    const int _b = (SBUF)*32768 + (SAB)*16384 + (SHALF)*8192; \
    gld16(_s + (size_t)(SHALF)*128*TD + (SKOFS) + roff[0], &lds[_b + t*8]); \
    gld16(_s + (size_t)(SHALF)*128*TD + (SKOFS) + roff[1], &lds[_b + (512+t)*8]); }

#define LD_AF(DST, BUF, QA) { \
    _Pragma("unroll") for (int m = 0; m < 4; ++m) \
    _Pragma("unroll") for (int kk = 0; kk < 2; ++kk) \
      DST[m][kk] = *(const bf16x8*)&lds[(BUF)*32768 + (QA)*8192 + ((wm*4+m)*2+kk)*512 + llo]; }

#define LD_BQ(DST, BUF, QB) { \
    _Pragma("unroll") for (int n = 0; n < 2; ++n) \
    _Pragma("unroll") for (int kk = 0; kk < 2; ++kk) \
      DST[n][kk] = *(const bf16x8*)&lds[(BUF)*32768 + 16384 + (QB)*8192 + ((wn*2+n)*2+kk)*512 + llo]; }

#define MF(AF, BQ, QA, QB) { \
    _Pragma("unroll") for (int kk = 0; kk < 2; ++kk) \
    _Pragma("unroll") for (int m = 0; m < 4; ++m) \
    _Pragma("unroll") for (int n = 0; n < 2; ++n) \
      acc[QA][QB][m][n] = __builtin_amdgcn_mfma_f32_16x16x32_bf16( \
          AF[m][kk], BQ[n][kk], acc[QA][QB][m][n], 0,0,0); }

  const int NT = K / 64;      // 64 K-tiles

  // prologue: b0 fully (tau=0), b1 h0 (tau=1); b1 h1 staged by P1/P2
  STG(0,0,0, 0);  SCHED0;
  STG(0,1,0, 0);  SCHED0;
  STG(0,0,1, 0);  SCHED0;
  STG(0,1,1, 0);  SCHED0;
  STG(1,0,0, 64); SCHED0;
  STG(1,1,0, 64); SCHED0;
  VMCNT4; SBAR; SCHED0;       // b0 resident block-wide; b1.h0 in flight

  for (int i2 = 0; i2 < NT/2; ++i2) {
    const int k1c = (2*i2+1) * 64;
    const int k0n = (2*i2+2 < NT ? 2*i2+2 : NT-1) * 64;
    const int k1n = (2*i2+3 < NT ? 2*i2+3 : NT-1) * 64;

    // ---- group 0: compute buf0 ----
    // P1: self-load afP,bqP (buf0 published at end of prev P8)
    LD_AF(afP, 0, 0); LD_BQ(bqP, 0, 0);
    STG(1,0,1, k1c);
    SBAR; LGKM0; SCHED0;
    PRIO1; LD_BQ(bqQ, 0, 1); MF(afP, bqP, 0, 0); PRIO0;
    SBAR; SCHED0;
    // P2
    STG(1,1,1, k1c);
    SBAR; LGKM0; SCHED0;
    PRIO1; LD_AF(afQ, 0, 1); MF(afP, bqQ, 0, 1); PRIO0;
    SBAR; SCHED0;
    // P3
    STG(0,0,0, k0n);
    SBAR; LGKM0; SCHED0;
    PRIO1; MF(afQ, bqP, 1, 0); PRIO0;
    SBAR; SCHED0;
    // P4: vmcnt(4) publishes buf1 (h0 from prev P7/P8, h1 from P1/P2)
    STG(0,1,0, k0n);
    VMCNT4;
    SBAR; LGKM0; SCHED0;
    PRIO1; MF(afQ, bqQ, 1, 1); PRIO0;
    SBAR; SCHED0;

    // ---- group 1: compute buf1 ----
    // P5: self-load (buf1 published at end of P4)
    LD_AF(afP, 1, 0); LD_BQ(bqP, 1, 0);
    STG(0,0,1, k0n);
    SBAR; LGKM0; SCHED0;
    PRIO1; LD_BQ(bqQ, 1, 1); MF(afP, bqP, 0, 0); PRIO0;
    SBAR; SCHED0;
    // P6
    STG(0,1,1, k0n);
    SBAR; LGKM0; SCHED0;
    PRIO1; LD_AF(afQ, 1, 1); MF(afP, bqQ, 0, 1); PRIO0;
    SBAR; SCHED0;
    // P7
    STG(1,0,0, k1n);
    SBAR; LGKM0; SCHED0;
    PRIO1; MF(afQ, bqP, 1, 0); PRIO0;
    SBAR; SCHED0;
    // P8: vmcnt(4) publishes buf0' (staged P3..P6)
    STG(1,1,0, k1n);
    VMCNT4;
    SBAR; LGKM0; SCHED0;
    PRIO1; MF(afQ, bqQ, 1, 1); PRIO0;
    SBAR; SCHED0;
  }
#undef MF
#undef LD_BQ
#undef LD_AF
#undef STG

  VMCNT0;   // drain pending gld16 before LDS reuse / kernel end

  // -------- epilogues --------
  if constexpr (MODE == 2) {
    // V^T [B,H,HD,S]: 8 passes over (qb,n); slab [64 cols][256 rows] in LDS.
    SBAR;
    const int b = m0 >> 11, sbase = m0 & (TS - 1);
#pragma unroll
    for (int qb = 0; qb < 2; ++qb)
#pragma unroll
      for (int n = 0; n < 2; ++n) {
        __syncthreads();
#pragma unroll
        for (int qa = 0; qa < 2; ++qa)
#pragma unroll
          for (int m = 0; m < 4; ++m) {
            int lcol = wn * 16 + lr;
            int srow = qa * 128 + wm * 64 + m * 16 + lh * 4;
            ushort4 o;
            o.x = f2bf(acc[qa][qb][m][n][0]); o.y = f2bf(acc[qa][qb][m][n][1]);
            o.z = f2bf(acc[qa][qb][m][n][2]); o.w = f2bf(acc[qa][qb][m][n][3]);
            *(ushort4*)&lds[lcol * 268 + srow] = o;
          }
        __syncthreads();
#pragma unroll
        for (int rr = 0; rr < 4; ++rr) {
          int idx = rr * 512 + t;              // 2048 chunks: 64 cols x 32 x 16B
          int dl = idx >> 5, sc = (idx & 31) * 8;
          uint4 v = *(const uint4*)&lds[dl * 268 + sc];
          int d = n0 + qb * 128 + (dl >> 4) * 32 + n * 16 + (dl & 15);
          *(uint4*)((unsigned short*)out +
                    ((size_t)((b * TH + (d >> 8)) * THD + (d & 255))) * TS + sbase + sc) = v;
        }
      }
  } else {
#pragma unroll
    for (int qa = 0; qa < 2; ++qa)
#pragma unroll
      for (int qb = 0; qb < 2; ++qb)
#pragma unroll
        for (int m = 0; m < 4; ++m)
#pragma unroll
          for (int n = 0; n < 2; ++n)
#pragma unroll
            for (int r = 0; r < 4; ++r) {
              int row = m0 + qa * 128 + wm * 64 + m * 16 + lh * 4 + r;
              int col = n0 + qb * 128 + wn * 32 + n * 16 + lr;
              float x = acc[qa][qb][m][n][r];
              if constexpr (MODE == 0) {
                ((float*)out)[(size_t)row * TD + col] = x;
              } else {
                float part = __shfl_xor(x, 1, 64);
                int s = row & (TS - 1), b = row >> 11;
                int h = col >> 8, d = col & 255;
                float val = x;
                if (d < TROT) {
                  float cc = cosp[s * TROT + d], ss = sinp[s * TROT + d];
                  val = x * cc + ((d & 1) ? part : -part) * ss;
                }
                ((unsigned short*)out)[((size_t)(b * TH + h) * TS + s) * THD + d] = f2bf(val);
              }
            }
  }
}

// ---------------- causal flash attention, KVBLK=64 (unchanged) -------------
__global__ __launch_bounds__(256, 2) void k_fattn(
    const unsigned short* __restrict__ Qt, const unsigned short* __restrict__ Kt,
    const unsigned short* __restrict__ Vt, unsigned short* __restrict__ O)
{
  extern __shared__ unsigned short sh[];   // K 32KB | V 32KB | Ps 9KB
  const int t = threadIdx.x, w = t >> 6, l = t & 63, lr = l & 15, lh = l >> 4;
  const int bh = blockIdx.x;
  const int qb = (gridDim.y - 1) - blockIdx.y;   // LPT: heaviest first
  const int q0 = qb * 64;
  const int jmax = qb;

  const unsigned short* kbase = Kt + (size_t)bh * TS * THD;
  const unsigned short* vbase = Vt + (size_t)bh * THD * TS;

  const int llo = lr * 32 + ((lh ^ ((lr >> 1) & 3)) * 8);

  int koff[8], voff[8];
#pragma unroll
  for (int it = 0; it < 8; ++it) {
    int c = it * 256 + t;
    int row = (c >> 2) & 15;
    int scc = (c & 3) ^ ((row >> 1) & 3);
    koff[it] = (((c >> 9) & 3) * 16 + row) * THD + ((c >> 6) & 7) * 32 + scc * 8;
    voff[it] = (((c >> 6) & 15) * 16 + row) * TS + ((c >> 10) & 1) * 32 + scc * 8;
  }

  bf16x8 qf[8];
  const unsigned short* qp = Qt + ((size_t)bh * TS + q0 + w * 16 + lr) * THD;
#pragma unroll
  for (int kk = 0; kk < 8; ++kk) qf[kk] = *(const bf16x8*)(qp + kk * 32 + lh * 8);

  f32x4 oacc[16];
#pragma unroll
  for (int i = 0; i < 16; ++i) oacc[i] = 0.f;
  float mrow[4] = {-__builtin_inff(), -__builtin_inff(), -__builtin_inff(), -__builtin_inff()};
  float lrow[4] = {0.f, 0.f, 0.f, 0.f};

#pragma unroll
  for (int it = 0; it < 8; ++it) gld16(kbase + koff[it], &sh[(it*256 + t) * 8]);
#pragma unroll
  for (int it = 0; it < 8; ++it) gld16(vbase + voff[it], &sh[16384 + (it*256 + t) * 8]);

  for (int j = 0; j <= jmax; ++j) {
    const bool nx = (j < jmax);
    VMCNT8; SBAR; SCHED0;

    f32x4 sacc[4];
#pragma unroll
    for (int nt = 0; nt < 4; ++nt) sacc[nt] = 0.f;
    __builtin_amdgcn_s_setprio(1);
#pragma unroll
    for (int kk = 0; kk < 8; ++kk)          // kk-outer: 4 independent MFMAs
#pragma unroll
      for (int nt = 0; nt < 4; ++nt) {
        bf16x8 kf = *(const bf16x8*)&sh[(nt*8 + kk)*512 + llo];
        sacc[nt] = __builtin_amdgcn_mfma_f32_16x16x32_bf16(qf[kk], kf, sacc[nt], 0, 0, 0);
      }
    __builtin_amdgcn_s_setprio(0);
    LGKM0; SBAR; SCHED0;
    if (nx) {
      const unsigned short* kj = kbase + (size_t)(j + 1) * 64 * THD;
#pragma unroll
      for (int it = 0; it < 8; ++it) gld16(kj + koff[it], &sh[(it*256 + t) * 8]);
    }

    float p[4][4], tmax[4];
    const int qrow0 = q0 + w * 16 + lh * 4;
#pragma unroll
    for (int r = 0; r < 4; ++r) tmax[r] = -__builtin_inff();
#pragma unroll
    for (int nt = 0; nt < 4; ++nt) {
      int kpos = j * 64 + nt * 16 + lr;
#pragma unroll
      for (int r = 0; r < 4; ++r) {
        float sv = sacc[nt][r] * 0.0625f;
        if (kpos > qrow0 + r) sv = -__builtin_inff();
        p[nt][r] = sv;
        tmax[r] = fmaxf(tmax[r], sv);
      }
    }
#pragma unroll
    for (int off = 1; off < 16; off <<= 1)
#pragma unroll
      for (int r = 0; r < 4; ++r) tmax[r] = fmaxf(tmax[r], __shfl_xor(tmax[r], off, 64));

    float g = fmaxf(fmaxf(tmax[0] - mrow[0], tmax[1] - mrow[1]),
                    fmaxf(tmax[2] - mrow[2], tmax[3] - mrow[3]));
    if (__any(g > 8.f)) {
      float alpha[4];
#pragma unroll
      for (int r = 0; r < 4; ++r) {
        float mn = fmaxf(mrow[r], tmax[r]);
        alpha[r] = __expf(mrow[r] - mn);
        mrow[r] = mn;
        lrow[r] *= alpha[r];
      }
#pragma unroll
      for (int i = 0; i < 16; ++i)
#pragma unroll
        for (int r = 0; r < 4; ++r) oacc[i][r] *= alpha[r];
    }

    float tsum[4] = {0.f, 0.f, 0.f, 0.f};
#pragma unroll
    for (int nt = 0; nt < 4; ++nt)
#pragma unroll
      for (int r = 0; r < 4; ++r) {
        float pe = __expf(p[nt][r] - mrow[r]);
        p[nt][r] = pe;
        tsum[r] += pe;
      }
#pragma unroll
    for (int off = 1; off < 16; off <<= 1)
#pragma unroll
      for (int r = 0; r < 4; ++r) tsum[r] += __shfl_xor(tsum[r], off, 64);
#pragma unroll
    for (int r = 0; r < 4; ++r) lrow[r] += tsum[r];

    const int wb = 32768 + w * 1152;
#pragma unroll
    for (int nt = 0; nt < 4; ++nt)
#pragma unroll
      for (int r = 0; r < 4; ++r)
        sh[wb + (lh*4 + r)*72 + nt*16 + lr] = f2bf(p[nt][r]);
    bf16x8 pfr0 = *(const bf16x8*)&sh[wb + lr*72 + lh*8];
    bf16x8 pfr1 = *(const bf16x8*)&sh[wb + lr*72 + 32 + lh*8];

    if (nx) { VMCNT8; } else { VMCNT0; }
    SBAR; SCHED0;
    __builtin_amdgcn_s_setprio(1);
#pragma unroll
    for (int dt = 0; dt < 16; ++dt) {
      bf16x8 vf = *(const bf16x8*)&sh[16384 + dt*512 + llo];
      oacc[dt] = __builtin_amdgcn_mfma_f32_16x16x32_bf16(pfr0, vf, oacc[dt], 0, 0, 0);
    }
#pragma unroll
    for (int dt = 0; dt < 16; ++dt) {
      bf16x8 vf = *(const bf16x8*)&sh[16384 + (16 + dt)*512 + llo];
      oacc[dt] = __builtin_amdgcn_mfma_f32_16x16x32_bf16(pfr1, vf, oacc[dt], 0, 0, 0);
    }
    __builtin_amdgcn_s_setprio(0);
    LGKM0; SBAR; SCHED0;
    if (nx) {
      const unsigned short* vj = vbase + (size_t)(j + 1) * 64;
#pragma unroll
      for (int it = 0; it < 8; ++it) gld16(vj + voff[it], &sh[16384 + (it*256 + t) * 8]);
    }
  }

  const int b = bh >> 4, h = bh & 15;
  float inv[4];
#pragma unroll
  for (int r = 0; r < 4; ++r) inv[r] = 1.f / lrow[r];
#pragma unroll
  for (int dt = 0; dt < 16; ++dt)
#pragma unroll
    for (int r = 0; r < 4; ++r) {
      int s = q0 + w * 16 + lh * 4 + r;
      O[((size_t)(b * TS + s) * TH + h) * THD + dt * 16 + lr] = f2bf(oacc[dt][r] * inv[r]);
    }
}

// ---------------- launch ----------------
extern "C" void kernel_launch(void* const* d_in, const int* in_sizes, int n_in,
                              void* d_out, int out_size, void* d_ws, size_t ws_size,
                              hipStream_t stream) {
  const float* hs   = (const float*)d_in[0];
  const float* sinp = (const float*)d_in[1];
  const float* cosp = (const float*)d_in[2];
  const float* Wq   = (const float*)d_in[3];
  const float* Wk   = (const float*)d_in[4];
  const float* Wv   = (const float*)d_in[5];
  const float* Wo   = (const float*)d_in[6];

  const size_t NE = (size_t)TM * TD;
  const size_t BYTES = NE * 2;
  char* ws = (char*)d_ws;
  unsigned short* hsb = (unsigned short*)(ws + 0*BYTES);
  unsigned short* Wqb = (unsigned short*)(ws + 1*BYTES);
  unsigned short* Wkb = (unsigned short*)(ws + 2*BYTES);
  unsigned short* Wvb = (unsigned short*)(ws + 3*BYTES);
  unsigned short* Wob = (unsigned short*)(ws + 4*BYTES);
  unsigned short* Qt  = (unsigned short*)(ws + 5*BYTES);  // [B,H,S,HD]
  unsigned short* Ktb = (unsigned short*)(ws + 6*BYTES);  // [B,H,S,HD]
  unsigned short* Vtb = (unsigned short*)(ws + 7*BYTES);  // [B,H,HD,S]
  unsigned short* Ob  = (unsigned short*)(ws + 8*BYTES);  // [B,S,H,HD] == [M,D]

  k_cvt5<<<81920, 256, 0, stream>>>(hs, Wq, Wk, Wv, Wo, hsb);

  k_gemm<1><<<256, 512, 131072, stream>>>(hsb, Wqb, (void*)Qt,  sinp, cosp);
  k_gemm<1><<<256, 512, 131072, stream>>>(hsb, Wkb, (void*)Ktb, sinp, cosp);
  k_gemm<2><<<256, 512, 131072, stream>>>(hsb, Wvb, (void*)Vtb, nullptr, nullptr);

  k_fattn<<<dim3(TB*TH, TS/64), 256, 74752, stream>>>(Qt, Ktb, Vtb, Ob);

  k_gemm<0><<<256, 512, 131072, stream>>>(Ob, Wob, d_out, nullptr, nullptr);
}

// Round 10
// 699.774 us; speedup vs baseline: 1.9827x; 1.0330x over previous
//
#include <hip/hip_runtime.h>
#include <cstdint>
#include <cstddef>

#define TB 2
#define TS 2048
#define TD 4096
#define TH 16
#define THD 256
#define TROT 64
#define TM (TB*TS)

typedef __attribute__((ext_vector_type(8))) short bf16x8;
typedef __attribute__((ext_vector_type(4))) float f32x4;

#define LGKM0  asm volatile("s_waitcnt lgkmcnt(0)" ::: "memory")
#define VMCNT8 asm volatile("s_waitcnt vmcnt(8)" ::: "memory")
#define VMCNT4 asm volatile("s_waitcnt vmcnt(4)" ::: "memory")
#define VMCNT0 asm volatile("s_waitcnt vmcnt(0)" ::: "memory")
#define SBAR   __builtin_amdgcn_s_barrier()
#define SCHED0 __builtin_amdgcn_sched_barrier(0)
#define PRIO1  __builtin_amdgcn_s_setprio(1)
#define PRIO0  __builtin_amdgcn_s_setprio(0)

__device__ __forceinline__ unsigned short f2bf(float f) {
  union { float f; unsigned u; } v; v.f = f;
  return (unsigned short)((v.u + 0x7fffu + ((v.u >> 16) & 1u)) >> 16);
}

__device__ __forceinline__ void gld16(const void* g, void* l) {
  __builtin_amdgcn_global_load_lds(
      (const __attribute__((address_space(1))) unsigned int*)g,
      (__attribute__((address_space(3))) unsigned int*)l, 16, 0, 0);
}

// ---------------- fused fp32 -> bf16 convert (5 tensors, dst contiguous) ----
__global__ __launch_bounds__(256) void k_cvt5(
    const float* __restrict__ s0, const float* __restrict__ s1,
    const float* __restrict__ s2, const float* __restrict__ s3,
    const float* __restrict__ s4, unsigned short* __restrict__ dst) {
  int i = blockIdx.x * 256 + threadIdx.x;          // 5 * 2^22 chunks of 4 floats
  int tsel = i >> 22, il = i & 4194303;
  const float* s = tsel == 0 ? s0 : tsel == 1 ? s1 : tsel == 2 ? s2 : tsel == 3 ? s3 : s4;
  float4 v = reinterpret_cast<const float4*>(s)[il];
  ushort4 o;
  o.x = f2bf(v.x); o.y = f2bf(v.y); o.z = f2bf(v.z); o.w = f2bf(v.w);
  *reinterpret_cast<ushort4*>(dst + (size_t)i * 4) = o;
}

// ======== shared 8-phase main-loop macros (BK=64, 256x256, 8 waves) ========
#define GSTG(SBUF, SAB, SHALF, SKOFS) { \
    const unsigned short* _s = (SAB) ? srcB : srcA; \
    const int _b = (SBUF)*32768 + (SAB)*16384 + (SHALF)*8192; \
    gld16(_s + (size_t)(SHALF)*128*TD + (SKOFS) + roff[0], &lds[_b + t*8]); \
    gld16(_s + (size_t)(SHALF)*128*TD + (SKOFS) + roff[1], &lds[_b + (512+t)*8]); }

#define GLD_AF(DST, BUF, QA) { \
    _Pragma("unroll") for (int m = 0; m < 4; ++m) \
    _Pragma("unroll") for (int kk = 0; kk < 2; ++kk) \
      DST[m][kk] = *(const bf16x8*)&lds[(BUF)*32768 + (QA)*8192 + ((wm*4+m)*2+kk)*512 + llo]; }

#define GLD_BQ(DST, BUF, QB) { \
    _Pragma("unroll") for (int n = 0; n < 2; ++n) \
    _Pragma("unroll") for (int kk = 0; kk < 2; ++kk) \
      DST[n][kk] = *(const bf16x8*)&lds[(BUF)*32768 + 16384 + (QB)*8192 + ((wn*2+n)*2+kk)*512 + llo]; }

#define GMF(AF, BQ, QA, QB) { \
    _Pragma("unroll") for (int kk = 0; kk < 2; ++kk) \
    _Pragma("unroll") for (int m = 0; m < 4; ++m) \
    _Pragma("unroll") for (int n = 0; n < 2; ++n) \
      acc[QA][QB][m][n] = __builtin_amdgcn_mfma_f32_16x16x32_bf16( \
          AF[m][kk], BQ[n][kk], acc[QA][QB][m][n], 0,0,0); }

#define GEMM_MAIN_LOOP \
  GSTG(0,0,0, 0);  SCHED0; \
  GSTG(0,1,0, 0);  SCHED0; \
  GSTG(0,0,1, 0);  SCHED0; \
  GSTG(0,1,1, 0);  SCHED0; \
  GSTG(1,0,0, 64); SCHED0; \
  GSTG(1,1,0, 64); SCHED0; \
  VMCNT4; SBAR; SCHED0; \
  for (int i2 = 0; i2 < NT/2; ++i2) { \
    const int k1c = (2*i2+1) * 64; \
    const int k0n = (2*i2+2 < NT ? 2*i2+2 : NT-1) * 64; \
    const int k1n = (2*i2+3 < NT ? 2*i2+3 : NT-1) * 64; \
    GLD_AF(afP, 0, 0); GLD_BQ(bqP, 0, 0); \
    GSTG(1,0,1, k1c); \
    SBAR; LGKM0; SCHED0; \
    PRIO1; GLD_BQ(bqQ, 0, 1); GMF(afP, bqP, 0, 0); PRIO0; \
    SBAR; SCHED0; \
    GSTG(1,1,1, k1c); \
    SBAR; LGKM0; SCHED0; \
    PRIO1; GLD_AF(afQ, 0, 1); GMF(afP, bqQ, 0, 1); PRIO0; \
    SBAR; SCHED0; \
    GSTG(0,0,0, k0n); \
    SBAR; LGKM0; SCHED0; \
    PRIO1; GMF(afQ, bqP, 1, 0); PRIO0; \
    SBAR; SCHED0; \
    GSTG(0,1,0, k0n); \
    VMCNT4; \
    SBAR; LGKM0; SCHED0; \
    PRIO1; GMF(afQ, bqQ, 1, 1); PRIO0; \
    SBAR; SCHED0; \
    GLD_AF(afP, 1, 0); GLD_BQ(bqP, 1, 0); \
    GSTG(0,0,1, k0n); \
    SBAR; LGKM0; SCHED0; \
    PRIO1; GLD_BQ(bqQ, 1, 1); GMF(afP, bqP, 0, 0); PRIO0; \
    SBAR; SCHED0; \
    GSTG(0,1,1, k0n); \
    SBAR; LGKM0; SCHED0; \
    PRIO1; GLD_AF(afQ, 1, 1); GMF(afP, bqQ, 0, 1); PRIO0; \
    SBAR; SCHED0; \
    GSTG(1,0,0, k1n); \
    SBAR; LGKM0; SCHED0; \
    PRIO1; GMF(afQ, bqP, 1, 0); PRIO0; \
    SBAR; SCHED0; \
    GSTG(1,1,0, k1n); \
    VMCNT4; \
    SBAR; LGKM0; SCHED0; \
    PRIO1; GMF(afQ, bqQ, 1, 1); PRIO0; \
    SBAR; SCHED0; \
  }

#define GEMM_PREAMBLE \
  const int K = TD; \
  const int t = threadIdx.x; \
  const int w = t >> 6, l = t & 63, lr = l & 15, lh = l >> 4; \
  const int wm = w >> 2, wn = w & 3; \
  const int llo = lr * 32 + ((lh ^ ((lr >> 1) & 3)) * 8); \
  int roff[2]; \
  _Pragma("unroll") \
  for (int it = 0; it < 2; ++it) { \
    int c = it * 512 + t; \
    int rl = (c >> 2) & 15; \
    roff[it] = (16 * (c >> 7) + rl) * K + ((c >> 6) & 1) * 32 + ((c & 3) ^ ((rl >> 1) & 3)) * 8; \
  } \
  f32x4 acc[2][2][4][2]; \
  _Pragma("unroll") \
  for (int qa = 0; qa < 2; ++qa) \
  _Pragma("unroll") \
    for (int qb = 0; qb < 2; ++qb) \
  _Pragma("unroll") \
      for (int m = 0; m < 4; ++m) \
  _Pragma("unroll") \
        for (int n = 0; n < 2; ++n) acc[qa][qb][m][n] = 0.f; \
  bf16x8 afP[4][2], afQ[4][2], bqP[2][2], bqQ[2][2]; \
  const int NT = K / 64;

// ---------------- merged QKV GEMM: 768 blocks, W = [Wq|Wk|Wv] ----------------
__global__ __launch_bounds__(512, 1) void k_gqkv(
    const unsigned short* __restrict__ A, const unsigned short* __restrict__ W,
    unsigned short* __restrict__ Qo, unsigned short* __restrict__ Ko,
    unsigned short* __restrict__ Vo,
    const float* __restrict__ sinp, const float* __restrict__ cosp)
{
  extern __shared__ unsigned short lds[];   // 131072 B
  // XCD swizzle: 768 = 8 x 96, bijective
  const int id = blockIdx.x;
  const int swz = (id & 7) * 96 + (id >> 3);
  const int m0 = (swz / 48) * 256, n0 = (swz % 48) * 256;

  GEMM_PREAMBLE
  const unsigned short* srcA = A + (size_t)m0 * K;
  const unsigned short* srcB = W + (size_t)n0 * K;

  GEMM_MAIN_LOOP

  VMCNT0;
  const int tsel = n0 >> 12;          // 0=Q, 1=K, 2=V (block-uniform)
  if (tsel == 2) {
    // V^T [B,H,HD,S] via LDS-bounce; d base = n0 - 8192
    SBAR;
    const int n0v = n0 - 8192;
    const int b = m0 >> 11, sbase = m0 & (TS - 1);
#pragma unroll
    for (int qb = 0; qb < 2; ++qb)
#pragma unroll
      for (int n = 0; n < 2; ++n) {
        __syncthreads();
#pragma unroll
        for (int qa = 0; qa < 2; ++qa)
#pragma unroll
          for (int m = 0; m < 4; ++m) {
            int lcol = wn * 16 + lr;
            int srow = qa * 128 + wm * 64 + m * 16 + lh * 4;
            ushort4 o;
            o.x = f2bf(acc[qa][qb][m][n][0]); o.y = f2bf(acc[qa][qb][m][n][1]);
            o.z = f2bf(acc[qa][qb][m][n][2]); o.w = f2bf(acc[qa][qb][m][n][3]);
            *(ushort4*)&lds[lcol * 268 + srow] = o;
          }
        __syncthreads();
#pragma unroll
        for (int rr = 0; rr < 4; ++rr) {
          int idx = rr * 512 + t;
          int dl = idx >> 5, sc = (idx & 31) * 8;
          uint4 v = *(const uint4*)&lds[dl * 268 + sc];
          int d = n0v + qb * 128 + (dl >> 4) * 32 + n * 16 + (dl & 15);
          *(uint4*)(Vo + ((size_t)((b * TH + (d >> 8)) * THD + (d & 255))) * TS + sbase + sc) = v;
        }
      }
  } else {
    unsigned short* outp = tsel ? Ko : Qo;
    const int nbase = n0 & 4095;
#pragma unroll
    for (int qa = 0; qa < 2; ++qa)
#pragma unroll
      for (int qb = 0; qb < 2; ++qb)
#pragma unroll
        for (int m = 0; m < 4; ++m)
#pragma unroll
          for (int n = 0; n < 2; ++n)
#pragma unroll
            for (int r = 0; r < 4; ++r) {
              int row = m0 + qa * 128 + wm * 64 + m * 16 + lh * 4 + r;
              int col = nbase + qb * 128 + wn * 32 + n * 16 + lr;
              float x = acc[qa][qb][m][n][r];
              float part = __shfl_xor(x, 1, 64);
              int s = row & (TS - 1), b = row >> 11;
              int h = col >> 8, d = col & 255;
              float val = x;
              if (d < TROT) {
                float cc = cosp[s * TROT + d], ss = sinp[s * TROT + d];
                val = x * cc + ((d & 1) ? part : -part) * ss;
              }
              outp[((size_t)(b * TH + h) * TS + s) * THD + d] = f2bf(val);
            }
  }
}

// ---------------- output-projection GEMM: fp32 out [M,N] ----------------
__global__ __launch_bounds__(512, 1) void k_gout(
    const unsigned short* __restrict__ A, const unsigned short* __restrict__ W,
    float* __restrict__ out)
{
  extern __shared__ unsigned short lds[];   // 131072 B
  const int id = blockIdx.x;                // 256 = 8 x 32, bijective
  const int swz = (id & 7) * 32 + (id >> 3);
  const int m0 = (swz >> 4) * 256, n0 = (swz & 15) * 256;

  GEMM_PREAMBLE
  const unsigned short* srcA = A + (size_t)m0 * K;
  const unsigned short* srcB = W + (size_t)n0 * K;

  GEMM_MAIN_LOOP

  VMCNT0;
#pragma unroll
  for (int qa = 0; qa < 2; ++qa)
#pragma unroll
    for (int qb = 0; qb < 2; ++qb)
#pragma unroll
      for (int m = 0; m < 4; ++m)
#pragma unroll
        for (int n = 0; n < 2; ++n)
#pragma unroll
          for (int r = 0; r < 4; ++r) {
            int row = m0 + qa * 128 + wm * 64 + m * 16 + lh * 4 + r;
            int col = n0 + qb * 128 + wn * 32 + n * 16 + lr;
            out[(size_t)row * TD + col] = acc[qa][qb][m][n][r];
          }
}

// ---------------- causal flash attention, KVBLK=64 --------------------------
// Lazy max-reduce (full 16-lane reduction only in the rare rescale branch)
// + deferred denominator (lane-partial lrow, reduced once in the epilogue).
__global__ __launch_bounds__(256, 2) void k_fattn(
    const unsigned short* __restrict__ Qt, const unsigned short* __restrict__ Kt,
    const unsigned short* __restrict__ Vt, unsigned short* __restrict__ O)
{
  extern __shared__ unsigned short sh[];   // K 32KB | V 32KB | Ps 9KB
  const int t = threadIdx.x, w = t >> 6, l = t & 63, lr = l & 15, lh = l >> 4;
  const int bh = blockIdx.x;
  const int qb = (gridDim.y - 1) - blockIdx.y;   // LPT: heaviest first
  const int q0 = qb * 64;
  const int jmax = qb;

  const unsigned short* kbase = Kt + (size_t)bh * TS * THD;
  const unsigned short* vbase = Vt + (size_t)bh * THD * TS;

  const int llo = lr * 32 + ((lh ^ ((lr >> 1) & 3)) * 8);

  int koff[8], voff[8];
#pragma unroll
  for (int it = 0; it < 8; ++it) {
    int c = it * 256 + t;
    int row = (c >> 2) & 15;
    int scc = (c & 3) ^ ((row >> 1) & 3);
    koff[it] = (((c >> 9) & 3) * 16 + row) * THD + ((c >> 6) & 7) * 32 + scc * 8;
    voff[it] = (((c >> 6) & 15) * 16 + row) * TS + ((c >> 10) & 1) * 32 + scc * 8;
  }

  bf16x8 qf[8];
  const unsigned short* qp = Qt + ((size_t)bh * TS + q0 + w * 16 + lr) * THD;
#pragma unroll
  for (int kk = 0; kk < 8; ++kk) qf[kk] = *(const bf16x8*)(qp + kk * 32 + lh * 8);

  f32x4 oacc[16];
#pragma unroll
  for (int i = 0; i < 16; ++i) oacc[i] = 0.f;
  float mrow[4] = {-__builtin_inff(), -__builtin_inff(), -__builtin_inff(), -__builtin_inff()};
  float lrow[4] = {0.f, 0.f, 0.f, 0.f};   // lane-partial denominators

#pragma unroll
  for (int it = 0; it < 8; ++it) gld16(kbase + koff[it], &sh[(it*256 + t) * 8]);
#pragma unroll
  for (int it = 0; it < 8; ++it) gld16(vbase + voff[it], &sh[16384 + (it*256 + t) * 8]);

  for (int j = 0; j <= jmax; ++j) {
    const bool nx = (j < jmax);
    VMCNT8; SBAR; SCHED0;

    f32x4 sacc[4];
#pragma unroll
    for (int nt = 0; nt < 4; ++nt) sacc[nt] = 0.f;
    PRIO1;
#pragma unroll
    for (int kk = 0; kk < 8; ++kk)          // kk-outer: 4 independent MFMAs
#pragma unroll
      for (int nt = 0; nt < 4; ++nt) {
        bf16x8 kf = *(const bf16x8*)&sh[(nt*8 + kk)*512 + llo];
        sacc[nt] = __builtin_amdgcn_mfma_f32_16x16x32_bf16(qf[kk], kf, sacc[nt], 0, 0, 0);
      }
    PRIO0;
    LGKM0; SBAR; SCHED0;
    if (nx) {
      const unsigned short* kj = kbase + (size_t)(j + 1) * 64 * THD;
#pragma unroll
      for (int it = 0; it < 8; ++it) gld16(kj + koff[it], &sh[(it*256 + t) * 8]);
    }

    // ---- online softmax (lazy max, deferred sum) ----
    float p[4][4];
    const int qrow0 = q0 + w * 16 + lh * 4;
#pragma unroll
    for (int nt = 0; nt < 4; ++nt) {
      int kpos = j * 64 + nt * 16 + lr;
#pragma unroll
      for (int r = 0; r < 4; ++r) {
        float sv = sacc[nt][r] * 0.0625f;
        if (kpos > qrow0 + r) sv = -__builtin_inff();
        p[nt][r] = sv;
      }
    }
    float lmax[4];
#pragma unroll
    for (int r = 0; r < 4; ++r)
      lmax[r] = fmaxf(fmaxf(p[0][r], p[1][r]), fmaxf(p[2][r], p[3][r]));
    float g = fmaxf(fmaxf(lmax[0] - mrow[0], lmax[1] - mrow[1]),
                    fmaxf(lmax[2] - mrow[2], lmax[3] - mrow[3]));
    if (__any(g > 8.f)) {                   // rare: full reduce + rescale
      float tmax[4] = {lmax[0], lmax[1], lmax[2], lmax[3]};
#pragma unroll
      for (int off = 1; off < 16; off <<= 1)
#pragma unroll
        for (int r = 0; r < 4; ++r) tmax[r] = fmaxf(tmax[r], __shfl_xor(tmax[r], off, 64));
      float alpha[4];
#pragma unroll
      for (int r = 0; r < 4; ++r) {
        float mn = fmaxf(mrow[r], tmax[r]);
        alpha[r] = __expf(mrow[r] - mn);
        mrow[r] = mn;
        lrow[r] *= alpha[r];
      }
#pragma unroll
      for (int i = 0; i < 16; ++i)
#pragma unroll
        for (int r = 0; r < 4; ++r) oacc[i][r] *= alpha[r];
    }
#pragma unroll
    for (int r = 0; r < 4; ++r) {
      float pe0 = __expf(p[0][r] - mrow[r]);
      float pe1 = __expf(p[1][r] - mrow[r]);
      float pe2 = __expf(p[2][r] - mrow[r]);
      float pe3 = __expf(p[3][r] - mrow[r]);
      p[0][r] = pe0; p[1][r] = pe1; p[2][r] = pe2; p[3][r] = pe3;
      lrow[r] += (pe0 + pe1) + (pe2 + pe3);   // lane-partial only
    }

    const int wb = 32768 + w * 1152;
#pragma unroll
    for (int nt = 0; nt < 4; ++nt)
#pragma unroll
      for (int r = 0; r < 4; ++r)
        sh[wb + (lh*4 + r)*72 + nt*16 + lr] = f2bf(p[nt][r]);
    bf16x8 pfr0 = *(const bf16x8*)&sh[wb + lr*72 + lh*8];
    bf16x8 pfr1 = *(const bf16x8*)&sh[wb + lr*72 + 32 + lh*8];

    if (nx) { VMCNT8; } else { VMCNT0; }
    SBAR; SCHED0;
    PRIO1;
#pragma unroll
    for (int dt = 0; dt < 16; ++dt) {
      bf16x8 vf = *(const bf16x8*)&sh[16384 + dt*512 + llo];
      oacc[dt] = __builtin_amdgcn_mfma_f32_16x16x32_bf16(pfr0, vf, oacc[dt], 0, 0, 0);
    }
#pragma unroll
    for (int dt = 0; dt < 16; ++dt) {
      bf16x8 vf = *(const bf16x8*)&sh[16384 + (16 + dt)*512 + llo];
      oacc[dt] = __builtin_amdgcn_mfma_f32_16x16x32_bf16(pfr1, vf, oacc[dt], 0, 0, 0);
    }
    PRIO0;
    LGKM0; SBAR; SCHED0;
    if (nx) {
      const unsigned short* vj = vbase + (size_t)(j + 1) * 64;
#pragma unroll
      for (int it = 0; it < 8; ++it) gld16(vj + voff[it], &sh[16384 + (it*256 + t) * 8]);
    }
  }

  // epilogue: reduce lane-partial denominators once, then write O
#pragma unroll
  for (int off = 1; off < 16; off <<= 1)
#pragma unroll
    for (int r = 0; r < 4; ++r) lrow[r] += __shfl_xor(lrow[r], off, 64);

  const int b = bh >> 4, h = bh & 15;
  float inv[4];
#pragma unroll
  for (int r = 0; r < 4; ++r) inv[r] = 1.f / lrow[r];
#pragma unroll
  for (int dt = 0; dt < 16; ++dt)
#pragma unroll
    for (int r = 0; r < 4; ++r) {
      int s = q0 + w * 16 + lh * 4 + r;
      O[((size_t)(b * TS + s) * TH + h) * THD + dt * 16 + lr] = f2bf(oacc[dt][r] * inv[r]);
    }
}

// ---------------- launch ----------------
extern "C" void kernel_launch(void* const* d_in, const int* in_sizes, int n_in,
                              void* d_out, int out_size, void* d_ws, size_t ws_size,
                              hipStream_t stream) {
  const float* hs   = (const float*)d_in[0];
  const float* sinp = (const float*)d_in[1];
  const float* cosp = (const float*)d_in[2];
  const float* Wq   = (const float*)d_in[3];
  const float* Wk   = (const float*)d_in[4];
  const float* Wv   = (const float*)d_in[5];
  const float* Wo   = (const float*)d_in[6];

  const size_t NE = (size_t)TM * TD;
  const size_t BYTES = NE * 2;
  char* ws = (char*)d_ws;
  unsigned short* hsb = (unsigned short*)(ws + 0*BYTES);
  unsigned short* Wqb = (unsigned short*)(ws + 1*BYTES);  // [Wq|Wk|Wv] contiguous
  unsigned short* Wob = (unsigned short*)(ws + 4*BYTES);
  unsigned short* Qt  = (unsigned short*)(ws + 5*BYTES);  // [B,H,S,HD]
  unsigned short* Ktb = (unsigned short*)(ws + 6*BYTES);  // [B,H,S,HD]
  unsigned short* Vtb = (unsigned short*)(ws + 7*BYTES);  // [B,H,HD,S]
  unsigned short* Ob  = (unsigned short*)(ws + 8*BYTES);  // [B,S,H,HD] == [M,D]

  k_cvt5<<<81920, 256, 0, stream>>>(hs, Wq, Wk, Wv, Wo, hsb);

  k_gqkv<<<768, 512, 131072, stream>>>(hsb, Wqb, Qt, Ktb, Vtb, sinp, cosp);

  k_fattn<<<dim3(TB*TH, TS/64), 256, 74752, stream>>>(Qt, Ktb, Vtb, Ob);

  k_gout<<<256, 512, 131072, stream>>>(Ob, Wob, (float*)d_out);
}